// Round 5
// baseline (361.690 us; speedup 1.0000x reference)
//
#include <hip/hip_runtime.h>
#include <hip/hip_bf16.h>
#include <math.h>

#define BB   128
#define NN   512
#define DIN  64
#define HH   256
#define DOUT 64
#define BNR  (BB * NN)          // 65536 rows

typedef float  f32x4  __attribute__((ext_vector_type(4)));
typedef __bf16 bf16x8 __attribute__((ext_vector_type(8)));

#define GLP(p)  ((const __attribute__((address_space(1))) void*)(p))
#define LDSP(p) ((__attribute__((address_space(3))) void*)(p))

// Haar/db1 'zero' DWT patterns, levels 1..3, FULL_LEN=8
__constant__ float PAT[3][8] = {
    {0.70710678f, 0.70710678f, 0.f, 0.f, 0.f, 0.f, 0.f, 0.f},
    {0.5f,        0.70710678f, 0.f, 0.5f, 0.f, 0.f, 0.f, 0.f},
    {0.35355339f, 0.70710678f, 0.f, 0.f, 0.f, 0.5f, 0.f, 0.35355339f}
};

__device__ __forceinline__ unsigned short f2bfu(float x) {
    __hip_bfloat16 b = __float2bfloat16(x);
    unsigned short u;
    __builtin_memcpy(&u, &b, 2);
    return u;
}
__device__ __forceinline__ float bf2f(unsigned short u) {
    unsigned int v = ((unsigned int)u) << 16;
    float f;
    __builtin_memcpy(&f, &v, 4);
    return f;
}

// ---------------------------------------------------------------------------
// Coalesced bf16 tile write via LDS staging (verified in round 4).
// ---------------------------------------------------------------------------
template<int BM, int BN, int FM, int FN>
__device__ __forceinline__ void write_tile(char* lds, f32x4 (&a)[FM][FN],
                                           __hip_bfloat16* __restrict__ C,
                                           long base, int N, int tid)
{
    const int wave = tid >> 6;
    const int lane = tid & 63;
    const int wm = wave >> 1, wn = wave & 1;
    const int lc = lane & 15;
    const int lr4 = (lane >> 4) << 2;
    __syncthreads();
    #pragma unroll
    for (int j = 0; j < FN; ++j) {
        int colb = (wn * (FN * 16) + j * 16 + lc) * 2;
        #pragma unroll
        for (int i = 0; i < FM; ++i) {
            int row0 = wm * (FM * 16) + i * 16 + lr4;
            #pragma unroll
            for (int r = 0; r < 4; ++r) {
                int row = row0 + r;
                *reinterpret_cast<unsigned short*>(
                    lds + row * (BN * 2) + (colb ^ (((row >> 2) & 3) << 5))) =
                    f2bfu(a[i][j][r]);
            }
        }
    }
    __syncthreads();
    const int TPR = BN / 8;          // threads per row (16B each)
    const int RPP = 256 / TPR;       // rows per pass
    #pragma unroll
    for (int p = 0; p < BM / RPP; ++p) {
        int row = p * RPP + tid / TPR;
        int cb = (tid % TPR) * 16;
        int pb = cb ^ (((row >> 2) & 3) << 5);
        uint4 v = *reinterpret_cast<const uint4*>(lds + row * (BN * 2) + pb);
        *reinterpret_cast<uint4*>(reinterpret_cast<char*>(C + base + (long)row * N) + cb) = v;
    }
}

// ---------------------------------------------------------------------------
// fp32 -> bf16 convert
// ---------------------------------------------------------------------------
__global__ __launch_bounds__(256) void cvt_k(const float* __restrict__ in,
                                             unsigned short* __restrict__ out, long n4)
{
    long gid = (long)blockIdx.x * 256 + threadIdx.x;
    long stride = (long)gridDim.x * 256;
    for (long i = gid; i < n4; i += stride) {
        float4 v = reinterpret_cast<const float4*>(in)[i];
        ushort4 u;
        u.x = f2bfu(v.x); u.y = f2bfu(v.y); u.z = f2bfu(v.z); u.w = f2bfu(v.w);
        reinterpret_cast<ushort4*>(out)[i] = u;
    }
}

// ---------------------------------------------------------------------------
// transpose-convert fp32 (R,C) -> bf16 (C,R) with optional per-source-row
// scale vector (used to fold wavelet coeff diag into the weight).
// ---------------------------------------------------------------------------
__device__ __forceinline__ void tcvt_body(const float* __restrict__ in,
                                          unsigned short* __restrict__ out,
                                          const float* __restrict__ cs,
                                          int R, int C, int r0, int c0)
{
    __shared__ float t[64][65];
    int tr = threadIdx.x >> 6;
    int tc = threadIdx.x & 63;
    #pragma unroll
    for (int i = 0; i < 16; ++i) {
        int r = i * 4 + tr;
        t[r][tc] = in[(long)(r0 + r) * C + c0 + tc];
    }
    __syncthreads();
    float sc = cs ? cs[r0 + tc] : 1.0f;
    #pragma unroll
    for (int i = 0; i < 16; ++i) {
        int r = i * 4 + tr;
        out[(long)(c0 + r) * R + r0 + tc] = f2bfu(t[tc][r] * sc);
    }
}

__global__ __launch_bounds__(256) void tcvt_k(const float* __restrict__ in,
                                              unsigned short* __restrict__ out,
                                              int R, int C, long sz)
{
    long base = (long)blockIdx.z * sz;
    tcvt_body(in + base, out + base, nullptr, R, C, blockIdx.y * 64, blockIdx.x * 64);
}

struct WTArgs {
    const float* src[9];
    unsigned short* dst[9];
    const float* cs[9];
    int R[9], C[9];
};
__global__ __launch_bounds__(256) void tcvt_w_k(WTArgs a)
{
    int wgt = blockIdx.y;
    int R = a.R[wgt], C = a.C[wgt];
    int tilesX = C >> 6;
    int tiles = (R >> 6) * tilesX;
    int t = blockIdx.x;
    if (t >= tiles) return;
    tcvt_body(a.src[wgt], a.dst[wgt], a.cs[wgt], R, C, (t / tilesX) * 64, (t % tilesX) * 64);
}

// ---------------------------------------------------------------------------
// wavelet coeff: coeff[f] = dot(Wnl[f], P[argmax(logits+gumb[f])])
// ---------------------------------------------------------------------------
__global__ void coeff_k(const float* __restrict__ logits, const float* __restrict__ gumb,
                        const float* __restrict__ Wnl, float* __restrict__ coeff)
{
    int f = threadIdx.x;
    float l0 = logits[0] + gumb[f * 3 + 0];
    float l1 = logits[1] + gumb[f * 3 + 1];
    float l2 = logits[2] + gumb[f * 3 + 2];
    int bl = 0;
    float bv = l0;
    if (l1 > bv) { bv = l1; bl = 1; }
    if (l2 > bv) { bv = l2; bl = 2; }
    float s = 0.f;
    #pragma unroll
    for (int t = 0; t < 8; ++t) s += Wnl[f * 8 + t] * PAT[bl][t];
    coeff[f] = s;
}

// crow[n] = bias[n] + sum_k bnl[k] * W[k*N+n]   (tiny, one block of N threads)
__global__ void crow_k(const float* __restrict__ W, const float* __restrict__ bnl,
                       const float* __restrict__ bias, float* __restrict__ out,
                       int K, int N)
{
    int n = threadIdx.x;
    if (n >= N) return;
    float s = bias[n];
    for (int k = 0; k < K; ++k) s += bnl[k] * W[(long)k * N + n];
    out[n] = s;
}

// ---------------------------------------------------------------------------
// Single MFMA bf16 GEMM (bf16 out, coalesced epilogue) — as round 4.
// ---------------------------------------------------------------------------
template<int BM, int BN, int FM, int FN>
__global__ __launch_bounds__(256) void gemm_bt_k(
    const __hip_bfloat16* __restrict__ A, const __hip_bfloat16* __restrict__ Bt,
    const float* __restrict__ bias, __hip_bfloat16* __restrict__ Cb,
    int M, int N, int K, long sA, long sB, long sC)
{
    __shared__ __attribute__((aligned(128))) char lds[(BM + BN) * 128];
    char* AsB = lds;
    char* BsB = lds + BM * 128;

    const long bz = blockIdx.z;
    const __hip_bfloat16* Ab = A + bz * sA;
    const __hip_bfloat16* Bb = Bt + bz * sB;

    const int m0 = blockIdx.y * BM;
    const int n0 = blockIdx.x * BN;
    const int tid  = threadIdx.x;
    const int wave = tid >> 6;
    const int lane = tid & 63;
    const int wm = wave >> 1, wn = wave & 1;

    const int NCH = (BM + BN) / 32;
    const int lr = lane >> 3;
    const int ls = lane & 7;

    f32x4 acc[FM][FN];
    #pragma unroll
    for (int i = 0; i < FM; ++i)
        #pragma unroll
        for (int j = 0; j < FN; ++j)
            acc[i][j] = (f32x4){0.f, 0.f, 0.f, 0.f};

    for (int k0 = 0; k0 < K; k0 += 64) {
        #pragma unroll
        for (int cc = 0; cc < NCH; ++cc) {
            int c = wave * NCH + cc;
            const __hip_bfloat16* src;
            char* ldsb;
            if (c < BM / 8) {
                int r = c * 8 + lr;
                ldsb = AsB + c * 1024;
                src = Ab + ((long)(m0 + r) * K + k0 + ((ls ^ (r & 7)) << 3));
            } else {
                int c2 = c - BM / 8;
                int r = c2 * 8 + lr;
                ldsb = BsB + c2 * 1024;
                src = Bb + ((long)(n0 + r) * K + k0 + ((ls ^ (r & 7)) << 3));
            }
            __builtin_amdgcn_global_load_lds(GLP(src), LDSP(ldsb), 16, 0, 0);
        }
        __syncthreads();

        #pragma unroll
        for (int ksl = 0; ksl < 2; ++ksl) {
            bf16x8 af[FM], bfr[FN];
            #pragma unroll
            for (int i = 0; i < FM; ++i) {
                int row = wm * (FM * 16) + i * 16 + (lane & 15);
                int off = (ksl * 64 + ((lane >> 4) << 4)) ^ ((row & 7) << 4);
                af[i] = *reinterpret_cast<const bf16x8*>(AsB + row * 128 + off);
            }
            #pragma unroll
            for (int j = 0; j < FN; ++j) {
                int row = wn * (FN * 16) + j * 16 + (lane & 15);
                int off = (ksl * 64 + ((lane >> 4) << 4)) ^ ((row & 7) << 4);
                bfr[j] = *reinterpret_cast<const bf16x8*>(BsB + row * 128 + off);
            }
            #pragma unroll
            for (int i = 0; i < FM; ++i)
                #pragma unroll
                for (int j = 0; j < FN; ++j)
                    acc[i][j] = __builtin_amdgcn_mfma_f32_16x16x32_bf16(
                        af[i], bfr[j], acc[i][j], 0, 0, 0);
        }
        __syncthreads();
    }

    const int lc = lane & 15;
    #pragma unroll
    for (int j = 0; j < FN; ++j) {
        int col = n0 + wn * (FN * 16) + j * 16 + lc;
        float bv = bias ? bias[col] : 0.0f;
        #pragma unroll
        for (int i = 0; i < FM; ++i)
            #pragma unroll
            for (int r = 0; r < 4; ++r)
                acc[i][j][r] += bv;
    }
    write_tile<BM, BN, FM, FN>(lds, acc, Cb, bz * sC + (long)m0 * N + n0, N, tid);
}

// ---------------------------------------------------------------------------
// Dual MFMA GEMM + in-register diff (round-4 structure, used for dual0)
// ---------------------------------------------------------------------------
template<int BM, int BN, int FM, int FN>
__global__ __launch_bounds__(256) void dual_k(
    const __hip_bfloat16* __restrict__ A1, const __hip_bfloat16* __restrict__ B1t,
    const float* __restrict__ bias1,
    const __hip_bfloat16* __restrict__ A2, const __hip_bfloat16* __restrict__ B2t,
    const float* __restrict__ bias2,
    __hip_bfloat16* __restrict__ C1, __hip_bfloat16* __restrict__ C2,
    float* __restrict__ partial,
    int M, int N, int K1, int K2)
{
    __shared__ __attribute__((aligned(128))) char lds[(BM + BN) * 128];
    char* AsB = lds;
    char* BsB = lds + BM * 128;

    const int m0 = blockIdx.y * BM;
    const int n0 = blockIdx.x * BN;
    const int tid  = threadIdx.x;
    const int wave = tid >> 6;
    const int lane = tid & 63;
    const int wm = wave >> 1, wn = wave & 1;

    const int NCH = (BM + BN) / 32;
    const int lr = lane >> 3;
    const int ls = lane & 7;

    f32x4 acc[2][FM][FN];
    #pragma unroll
    for (int p = 0; p < 2; ++p)
        #pragma unroll
        for (int i = 0; i < FM; ++i)
            #pragma unroll
            for (int j = 0; j < FN; ++j)
                acc[p][i][j] = (f32x4){0.f, 0.f, 0.f, 0.f};

    #pragma unroll
    for (int ph = 0; ph < 2; ++ph) {
        const __hip_bfloat16* Ab = ph ? A2 : A1;
        const __hip_bfloat16* Bb = ph ? B2t : B1t;
        const int K = ph ? K2 : K1;

        for (int k0 = 0; k0 < K; k0 += 64) {
            #pragma unroll
            for (int cc = 0; cc < NCH; ++cc) {
                int c = wave * NCH + cc;
                const __hip_bfloat16* src;
                char* ldsb;
                if (c < BM / 8) {
                    int r = c * 8 + lr;
                    ldsb = AsB + c * 1024;
                    src = Ab + ((long)(m0 + r) * K + k0 + ((ls ^ (r & 7)) << 3));
                } else {
                    int c2 = c - BM / 8;
                    int r = c2 * 8 + lr;
                    ldsb = BsB + c2 * 1024;
                    src = Bb + ((long)(n0 + r) * K + k0 + ((ls ^ (r & 7)) << 3));
                }
                __builtin_amdgcn_global_load_lds(GLP(src), LDSP(ldsb), 16, 0, 0);
            }
            __syncthreads();

            #pragma unroll
            for (int ksl = 0; ksl < 2; ++ksl) {
                bf16x8 af[FM], bfr[FN];
                #pragma unroll
                for (int i = 0; i < FM; ++i) {
                    int row = wm * (FM * 16) + i * 16 + (lane & 15);
                    int off = (ksl * 64 + ((lane >> 4) << 4)) ^ ((row & 7) << 4);
                    af[i] = *reinterpret_cast<const bf16x8*>(AsB + row * 128 + off);
                }
                #pragma unroll
                for (int j = 0; j < FN; ++j) {
                    int row = wn * (FN * 16) + j * 16 + (lane & 15);
                    int off = (ksl * 64 + ((lane >> 4) << 4)) ^ ((row & 7) << 4);
                    bfr[j] = *reinterpret_cast<const bf16x8*>(BsB + row * 128 + off);
                }
                #pragma unroll
                for (int i = 0; i < FM; ++i)
                    #pragma unroll
                    for (int j = 0; j < FN; ++j)
                        acc[ph][i][j] = __builtin_amdgcn_mfma_f32_16x16x32_bf16(
                            af[i], bfr[j], acc[ph][i][j], 0, 0, 0);
            }
            __syncthreads();
        }
    }

    const int lc  = lane & 15;
    float dsum = 0.f;
    #pragma unroll
    for (int j = 0; j < FN; ++j) {
        int col = n0 + wn * (FN * 16) + j * 16 + lc;
        float b1 = bias1 ? bias1[col] : 0.0f;
        float b2 = bias2 ? bias2[col] : 0.0f;
        #pragma unroll
        for (int i = 0; i < FM; ++i)
            #pragma unroll
            for (int r = 0; r < 4; ++r) {
                float v1 = acc[0][i][j][r] + b1;
                float v2 = acc[1][i][j][r] + b2;
                acc[0][i][j][r] = v1;
                acc[1][i][j][r] = v2;
                float d = v1 - v2;
                dsum += d * d;
            }
    }

    float* red = (float*)lds;
    red[tid] = dsum;
    __syncthreads();
    for (int o = 128; o > 0; o >>= 1) {
        if (tid < o) red[tid] += red[tid + o];
        __syncthreads();
    }
    if (tid == 0) partial[blockIdx.y * gridDim.x + blockIdx.x] = red[0];

    write_tile<BM, BN, FM, FN>(lds, acc[0], C1, (long)m0 * N + n0, N, tid);
    write_tile<BM, BN, FM, FN>(lds, acc[1], C2, (long)m0 * N + n0, N, tid);
}

// ---------------------------------------------------------------------------
// Triple MFMA GEMM (wavelet layer fused):
//   P0 = A0@B01, P1 = A1@B01, P2 = A2@B2
//   C1 = th*P0 + om*P1 + crow[col] (+ MIX: th*A0[m,col] + om*A1[m,col],
//        grabbed from the staged LDS A-tiles — zero extra global traffic)
//   C2 = P2 + bias2[col];  partial += (C1-C2)^2
// ---------------------------------------------------------------------------
template<int BM, int BN, int FM, int FN, bool MIX>
__global__ __launch_bounds__(256) void triple_k(
    const __hip_bfloat16* __restrict__ A0, const __hip_bfloat16* __restrict__ A1,
    const __hip_bfloat16* __restrict__ A2,
    const __hip_bfloat16* __restrict__ B01t, const __hip_bfloat16* __restrict__ B2t,
    const float* __restrict__ th_p, const float* __restrict__ crow,
    const float* __restrict__ bias2,
    __hip_bfloat16* __restrict__ C1, __hip_bfloat16* __restrict__ C2,
    float* __restrict__ partial,
    int M, int N, int K01, int K2)
{
    __shared__ __attribute__((aligned(128))) char lds[(BM + BN) * 128];
    char* AsB = lds;
    char* BsB = lds + BM * 128;

    const float th = th_p[0];
    const float om = 1.f - th;

    const int m0 = blockIdx.y * BM;
    const int n0 = blockIdx.x * BN;
    const int tid  = threadIdx.x;
    const int wave = tid >> 6;
    const int lane = tid & 63;
    const int wm = wave >> 1, wn = wave & 1;

    const int NCH = (BM + BN) / 32;
    const int lr = lane >> 3;
    const int ls = lane & 7;
    const int lc = lane & 15;
    const int lr4 = (lane >> 4) << 2;

    // the K-iteration whose staged A-tile contains this wave's output columns
    const int kgrab  = n0 + ((wn * FN * 16) & ~63);
    const int cgbase = wn * FN * 16 - (kgrab - n0);

    f32x4 acc[3][FM][FN];
    #pragma unroll
    for (int p = 0; p < 3; ++p)
        #pragma unroll
        for (int i = 0; i < FM; ++i)
            #pragma unroll
            for (int j = 0; j < FN; ++j)
                acc[p][i][j] = (f32x4){0.f, 0.f, 0.f, 0.f};

    unsigned int mixu[2][FM][FN][2];

    #pragma unroll
    for (int ph = 0; ph < 3; ++ph) {
        const __hip_bfloat16* Ab = (ph == 0) ? A0 : (ph == 1 ? A1 : A2);
        const __hip_bfloat16* Bb = (ph == 2) ? B2t : B01t;
        const int K = (ph == 2) ? K2 : K01;

        for (int k0 = 0; k0 < K; k0 += 64) {
            #pragma unroll
            for (int cc = 0; cc < NCH; ++cc) {
                int c = wave * NCH + cc;
                const __hip_bfloat16* src;
                char* ldsb;
                if (c < BM / 8) {
                    int r = c * 8 + lr;
                    ldsb = AsB + c * 1024;
                    src = Ab + ((long)(m0 + r) * K + k0 + ((ls ^ (r & 7)) << 3));
                } else {
                    int c2 = c - BM / 8;
                    int r = c2 * 8 + lr;
                    ldsb = BsB + c2 * 1024;
                    src = Bb + ((long)(n0 + r) * K + k0 + ((ls ^ (r & 7)) << 3));
                }
                __builtin_amdgcn_global_load_lds(GLP(src), LDSP(ldsb), 16, 0, 0);
            }
            __syncthreads();

            #pragma unroll
            for (int ksl = 0; ksl < 2; ++ksl) {
                bf16x8 af[FM], bfr[FN];
                #pragma unroll
                for (int i = 0; i < FM; ++i) {
                    int row = wm * (FM * 16) + i * 16 + lc;
                    int off = (ksl * 64 + ((lane >> 4) << 4)) ^ ((row & 7) << 4);
                    af[i] = *reinterpret_cast<const bf16x8*>(AsB + row * 128 + off);
                }
                #pragma unroll
                for (int j = 0; j < FN; ++j) {
                    int row = wn * (FN * 16) + j * 16 + lc;
                    int off = (ksl * 64 + ((lane >> 4) << 4)) ^ ((row & 7) << 4);
                    bfr[j] = *reinterpret_cast<const bf16x8*>(BsB + row * 128 + off);
                }
                #pragma unroll
                for (int i = 0; i < FM; ++i)
                    #pragma unroll
                    for (int j = 0; j < FN; ++j)
                        acc[ph][i][j] = __builtin_amdgcn_mfma_f32_16x16x32_bf16(
                            af[i], bfr[j], acc[ph][i][j], 0, 0, 0);
            }

            if constexpr (MIX) {
                if (ph < 2 && k0 == kgrab) {
                    #pragma unroll
                    for (int i = 0; i < FM; ++i) {
                        #pragma unroll
                        for (int j = 0; j < FN; ++j) {
                            int colk2 = (cgbase + j * 16 + lc) * 2;
                            #pragma unroll
                            for (int rh = 0; rh < 2; ++rh) {
                                int row0 = wm * (FM * 16) + i * 16 + lr4 + rh * 2;
                                unsigned short g0 = *reinterpret_cast<const unsigned short*>(
                                    AsB + row0 * 128 + (colk2 ^ ((row0 & 7) << 4)));
                                int row1 = row0 + 1;
                                unsigned short g1 = *reinterpret_cast<const unsigned short*>(
                                    AsB + row1 * 128 + (colk2 ^ ((row1 & 7) << 4)));
                                mixu[ph][i][j][rh] = (unsigned int)g0 | ((unsigned int)g1 << 16);
                            }
                        }
                    }
                }
            }
            __syncthreads();
        }
    }

    float dsum = 0.f;
    #pragma unroll
    for (int j = 0; j < FN; ++j) {
        int col = n0 + wn * (FN * 16) + j * 16 + lc;
        float cr = crow[col];
        float b2 = bias2 ? bias2[col] : 0.0f;
        #pragma unroll
        for (int i = 0; i < FM; ++i)
            #pragma unroll
            for (int r = 0; r < 4; ++r) {
                float v1 = th * acc[0][i][j][r] + om * acc[1][i][j][r] + cr;
                if constexpr (MIX) {
                    unsigned int u0 = mixu[0][i][j][r >> 1];
                    unsigned int u1 = mixu[1][i][j][r >> 1];
                    unsigned short a = (r & 1) ? (unsigned short)(u0 >> 16) : (unsigned short)u0;
                    unsigned short b = (r & 1) ? (unsigned short)(u1 >> 16) : (unsigned short)u1;
                    v1 += th * bf2f(a) + om * bf2f(b);
                }
                float v2 = acc[2][i][j][r] + b2;
                acc[0][i][j][r] = v1;
                acc[2][i][j][r] = v2;
                float d = v1 - v2;
                dsum += d * d;
            }
    }

    float* red = (float*)lds;
    red[tid] = dsum;
    __syncthreads();
    for (int o = 128; o > 0; o >>= 1) {
        if (tid < o) red[tid] += red[tid + o];
        __syncthreads();
    }
    if (tid == 0) partial[blockIdx.y * gridDim.x + blockIdx.x] = red[0];

    write_tile<BM, BN, FM, FN>(lds, acc[0], C1, (long)m0 * N + n0, N, tid);
    write_tile<BM, BN, FM, FN>(lds, acc[2], C2, (long)m0 * N + n0, N, tid);
}

// ---------------------------------------------------------------------------
// Dual GEMM with global mix-residual on C1 (for xg1):
//   C1 = A1@B1 + bias1 + th*mixA[m,n] + om*mixB[m,n]
//   C2 = A2@B2 + bias2;  partial += (C1-C2)^2
// C1 epilogue staged as f32 in LDS; mixA/mixB read coalesced (uint4).
// ---------------------------------------------------------------------------
template<int BM, int BN, int FM, int FN>
__global__ __launch_bounds__(256) void dualmix_k(
    const __hip_bfloat16* __restrict__ A1, const __hip_bfloat16* __restrict__ B1t,
    const float* __restrict__ bias1,
    const __hip_bfloat16* __restrict__ A2, const __hip_bfloat16* __restrict__ B2t,
    const float* __restrict__ bias2,
    const __hip_bfloat16* __restrict__ mixA, const __hip_bfloat16* __restrict__ mixB,
    const float* __restrict__ th_p,
    __hip_bfloat16* __restrict__ C1, __hip_bfloat16* __restrict__ C2,
    float* __restrict__ partial,
    int M, int N, int K1, int K2)
{
    __shared__ __attribute__((aligned(128))) char lds[BM * BN * 4];  // >= (BM+BN)*128
    char* AsB = lds;
    char* BsB = lds + BM * 128;

    const float th = th_p[0];
    const float om = 1.f - th;

    const int m0 = blockIdx.y * BM;
    const int n0 = blockIdx.x * BN;
    const int tid  = threadIdx.x;
    const int wave = tid >> 6;
    const int lane = tid & 63;
    const int wm = wave >> 1, wn = wave & 1;

    const int NCH = (BM + BN) / 32;
    const int lr = lane >> 3;
    const int ls = lane & 7;

    f32x4 acc[2][FM][FN];
    #pragma unroll
    for (int p = 0; p < 2; ++p)
        #pragma unroll
        for (int i = 0; i < FM; ++i)
            #pragma unroll
            for (int j = 0; j < FN; ++j)
                acc[p][i][j] = (f32x4){0.f, 0.f, 0.f, 0.f};

    #pragma unroll
    for (int ph = 0; ph < 2; ++ph) {
        const __hip_bfloat16* Ab = ph ? A2 : A1;
        const __hip_bfloat16* Bb = ph ? B2t : B1t;
        const int K = ph ? K2 : K1;

        for (int k0 = 0; k0 < K; k0 += 64) {
            #pragma unroll
            for (int cc = 0; cc < NCH; ++cc) {
                int c = wave * NCH + cc;
                const __hip_bfloat16* src;
                char* ldsb;
                if (c < BM / 8) {
                    int r = c * 8 + lr;
                    ldsb = AsB + c * 1024;
                    src = Ab + ((long)(m0 + r) * K + k0 + ((ls ^ (r & 7)) << 3));
                } else {
                    int c2 = c - BM / 8;
                    int r = c2 * 8 + lr;
                    ldsb = BsB + c2 * 1024;
                    src = Bb + ((long)(n0 + r) * K + k0 + ((ls ^ (r & 7)) << 3));
                }
                __builtin_amdgcn_global_load_lds(GLP(src), LDSP(ldsb), 16, 0, 0);
            }
            __syncthreads();

            #pragma unroll
            for (int ksl = 0; ksl < 2; ++ksl) {
                bf16x8 af[FM], bfr[FN];
                #pragma unroll
                for (int i = 0; i < FM; ++i) {
                    int row = wm * (FM * 16) + i * 16 + (lane & 15);
                    int off = (ksl * 64 + ((lane >> 4) << 4)) ^ ((row & 7) << 4);
                    af[i] = *reinterpret_cast<const bf16x8*>(AsB + row * 128 + off);
                }
                #pragma unroll
                for (int j = 0; j < FN; ++j) {
                    int row = wn * (FN * 16) + j * 16 + (lane & 15);
                    int off = (ksl * 64 + ((lane >> 4) << 4)) ^ ((row & 7) << 4);
                    bfr[j] = *reinterpret_cast<const bf16x8*>(BsB + row * 128 + off);
                }
                #pragma unroll
                for (int i = 0; i < FM; ++i)
                    #pragma unroll
                    for (int j = 0; j < FN; ++j)
                        acc[ph][i][j] = __builtin_amdgcn_mfma_f32_16x16x32_bf16(
                            af[i], bfr[j], acc[ph][i][j], 0, 0, 0);
            }
            __syncthreads();
        }
    }

    const int lc  = lane & 15;
    const int lr4 = (lane >> 4) << 2;
    float* ldsf = (float*)lds;
    const int TPR = BN / 8;          // threads per row (8 elems each)
    const int RPP = 256 / TPR;
    const int NP  = BM / RPP;        // coalesced passes

    // ---- pass 1: C1 = acc0 + bias1 + th*mixA + om*mixB ----
    #pragma unroll
    for (int j = 0; j < FN; ++j) {
        int col = n0 + wn * (FN * 16) + j * 16 + lc;
        float b1 = bias1 ? bias1[col] : 0.0f;
        #pragma unroll
        for (int i = 0; i < FM; ++i) {
            int rowb = wm * (FM * 16) + i * 16 + lr4;
            #pragma unroll
            for (int r = 0; r < 4; ++r)
                ldsf[(rowb + r) * BN + wn * (FN * 16) + j * 16 + lc] = acc[0][i][j][r] + b1;
        }
    }
    __syncthreads();

    float v1k[NP][8];
    float dsum = 0.f;
    #pragma unroll
    for (int p = 0; p < NP; ++p) {
        int row = p * RPP + tid / TPR;
        int cole = (tid % TPR) * 8;
        long gidx = (long)(m0 + row) * N + n0 + cole;
        uint4 ma = *reinterpret_cast<const uint4*>(mixA + gidx);
        uint4 mb = *reinterpret_cast<const uint4*>(mixB + gidx);
        unsigned int out[4];
        #pragma unroll
        for (int q = 0; q < 4; ++q) {
            unsigned int wa = (&ma.x)[q];
            unsigned int wb = (&mb.x)[q];
            float v0 = ldsf[row * BN + cole + q * 2]
                     + th * bf2f((unsigned short)wa) + om * bf2f((unsigned short)wb);
            float v1 = ldsf[row * BN + cole + q * 2 + 1]
                     + th * bf2f((unsigned short)(wa >> 16)) + om * bf2f((unsigned short)(wb >> 16));
            v1k[p][q * 2] = v0;
            v1k[p][q * 2 + 1] = v1;
            out[q] = (unsigned int)f2bfu(v0) | ((unsigned int)f2bfu(v1) << 16);
        }
        *reinterpret_cast<uint4*>(C1 + gidx) = make_uint4(out[0], out[1], out[2], out[3]);
    }
    __syncthreads();

    // ---- pass 2: C2 = acc1 + bias2; diff vs kept v1 ----
    #pragma unroll
    for (int j = 0; j < FN; ++j) {
        int col = n0 + wn * (FN * 16) + j * 16 + lc;
        float b2 = bias2 ? bias2[col] : 0.0f;
        #pragma unroll
        for (int i = 0; i < FM; ++i) {
            int rowb = wm * (FM * 16) + i * 16 + lr4;
            #pragma unroll
            for (int r = 0; r < 4; ++r)
                ldsf[(rowb + r) * BN + wn * (FN * 16) + j * 16 + lc] = acc[1][i][j][r] + b2;
        }
    }
    __syncthreads();

    #pragma unroll
    for (int p = 0; p < NP; ++p) {
        int row = p * RPP + tid / TPR;
        int cole = (tid % TPR) * 8;
        long gidx = (long)(m0 + row) * N + n0 + cole;
        unsigned int out[4];
        #pragma unroll
        for (int q = 0; q < 4; ++q) {
            float v0 = ldsf[row * BN + cole + q * 2];
            float v1 = ldsf[row * BN + cole + q * 2 + 1];
            float d0 = v1k[p][q * 2] - v0;
            float d1 = v1k[p][q * 2 + 1] - v1;
            dsum += d0 * d0 + d1 * d1;
            out[q] = (unsigned int)f2bfu(v0) | ((unsigned int)f2bfu(v1) << 16);
        }
        *reinterpret_cast<uint4*>(C2 + gidx) = make_uint4(out[0], out[1], out[2], out[3]);
    }
    __syncthreads();

    float* red = (float*)lds;
    red[tid] = dsum;
    __syncthreads();
    for (int o = 128; o > 0; o >>= 1) {
        if (tid < o) red[tid] += red[tid + o];
        __syncthreads();
    }
    if (tid == 0) partial[blockIdx.y * gridDim.x + blockIdx.x] = red[0];
}

// ---------------------------------------------------------------------------
// th = sigmoid(sum(partial)/n)
// ---------------------------------------------------------------------------
__global__ __launch_bounds__(256) void diff_final_k(
    const float* __restrict__ partial, int np, float* __restrict__ th_out, float inv_n)
{
    float s = 0.f;
    for (int i = threadIdx.x; i < np; i += 256) s += partial[i];
    __shared__ float sm[256];
    sm[threadIdx.x] = s;
    __syncthreads();
    for (int o = 128; o > 0; o >>= 1) {
        if (threadIdx.x < o) sm[threadIdx.x] += sm[threadIdx.x + o];
        __syncthreads();
    }
    if (threadIdx.x == 0) {
        float d = sm[0] * inv_n;
        th_out[0] = 1.f / (1.f + expf(-d));
    }
}

// ---------------------------------------------------------------------------
// mix + batched transpose, writes only xwT (b,H,N)
// ---------------------------------------------------------------------------
__global__ __launch_bounds__(256) void mixT_k(
    const unsigned short* __restrict__ h, const unsigned short* __restrict__ r,
    const float* __restrict__ th_p, unsigned short* __restrict__ xwT)
{
    const float th = th_p[0];
    const float om = 1.f - th;
    __shared__ float t[64][65];
    const long base = (long)blockIdx.z * NN * HH;
    const int r0 = blockIdx.y * 64;
    const int c0 = blockIdx.x * 64;
    const int tr = threadIdx.x >> 6;
    const int tc = threadIdx.x & 63;
    #pragma unroll
    for (int i = 0; i < 16; ++i) {
        int rr = i * 4 + tr;
        long idx = base + (long)(r0 + rr) * HH + c0 + tc;
        t[rr][tc] = th * bf2f(h[idx]) + om * bf2f(r[idx]);
    }
    __syncthreads();
    #pragma unroll
    for (int i = 0; i < 16; ++i) {
        int rr = i * 4 + tr;
        xwT[base + (long)(c0 + rr) * NN + r0 + tc] = f2bfu(t[tc][rr]);
    }
}

// ---------------------------------------------------------------------------
// final mix: out = th*h + (1-th)*r, fp32 out
// ---------------------------------------------------------------------------
__global__ __launch_bounds__(256) void mixfinal_k(
    const unsigned short* __restrict__ h, const unsigned short* __restrict__ r,
    const float* __restrict__ th_p, float* __restrict__ out, long n4)
{
    const float th = th_p[0];
    const float om = 1.f - th;
    long gid = (long)blockIdx.x * 256 + threadIdx.x;
    long stride = (long)gridDim.x * 256;
    for (long i = gid; i < n4; i += stride) {
        ushort4 hv = reinterpret_cast<const ushort4*>(h)[i];
        ushort4 rv = reinterpret_cast<const ushort4*>(r)[i];
        float4 o;
        o.x = th * bf2f(hv.x) + om * bf2f(rv.x);
        o.y = th * bf2f(hv.y) + om * bf2f(rv.y);
        o.z = th * bf2f(hv.z) + om * bf2f(rv.z);
        o.w = th * bf2f(hv.w) + om * bf2f(rv.w);
        reinterpret_cast<float4*>(out)[i] = o;
    }
}

// ---------------------------------------------------------------------------
extern "C" void kernel_launch(void* const* d_in, const int* in_sizes, int n_in,
                              void* d_out, int out_size, void* d_ws, size_t ws_size,
                              hipStream_t stream)
{
    const float* x       = (const float*)d_in[0];
    const float* adj     = (const float*)d_in[1];
    const float* Wres    = (const float*)d_in[2];
    const float* bres    = (const float*)d_in[3];
    const float* Wg0     = (const float*)d_in[4];
    const float* bg0     = (const float*)d_in[5];
    const float* Wrg0    = (const float*)d_in[6];
    const float* brg0    = (const float*)d_in[7];
    const float* logits0 = (const float*)d_in[8];
    const float* gumb0   = (const float*)d_in[9];
    const float* Wnl0    = (const float*)d_in[10];
    const float* bnl0    = (const float*)d_in[11];
    const float* Wwo0    = (const float*)d_in[12];
    const float* bwo0    = (const float*)d_in[13];
    const float* Wrw0    = (const float*)d_in[14];
    const float* brw0    = (const float*)d_in[15];
    const float* Wg1     = (const float*)d_in[16];
    const float* bg1     = (const float*)d_in[17];
    const float* Wrg1    = (const float*)d_in[18];
    const float* brg1    = (const float*)d_in[19];
    const float* logits1 = (const float*)d_in[20];
    const float* gumb1   = (const float*)d_in[21];
    const float* Wnl1    = (const float*)d_in[22];
    const float* bnl1    = (const float*)d_in[23];
    const float* Wwo1    = (const float*)d_in[24];
    const float* bwo1    = (const float*)d_in[25];
    const float* Wrw1    = (const float*)d_in[26];
    const float* brw1    = (const float*)d_in[27];

    float* out = (float*)d_out;

    // ---- workspace ----
    char* w = (char*)d_ws;
    auto alloc = [&](long bytes) { char* p = w; w += (bytes + 255) & ~255L; return p; };
    const long SLOT = (long)BNR * HH * 2;                 // 32 MB
    char* pool = alloc(5 * SLOT);                         // 160 MB
    __hip_bfloat16* Rbf  = (__hip_bfloat16*)alloc((long)BNR * DOUT * 2); // 8 MB
    __hip_bfloat16* adjb = (__hip_bfloat16*)alloc((long)NN * NN * 2);
    __hip_bfloat16* WT   = (__hip_bfloat16*)alloc(221184L * 2);
    float* partial = (float*)alloc(4096 * 4);
    float* th_s    = (float*)alloc(16);
    float* c0      = (float*)alloc(256 * 4);
    float* c1      = (float*)alloc(256 * 4);
    float* crow0   = (float*)alloc(256 * 4);
    float* crow1   = (float*)alloc(256 * 4);

    auto S = [&](int i) { return pool + (long)i * SLOT; };
    __hip_bfloat16* xbf  = (__hip_bfloat16*)S(1);
    __hip_bfloat16* xT   = (__hip_bfloat16*)(S(1) + (long)BNR * DIN * 2);
    __hip_bfloat16* T0   = (__hip_bfloat16*)S(0);
    __hip_bfloat16* xg   = (__hip_bfloat16*)S(2);
    __hip_bfloat16* rg   = (__hip_bfloat16*)S(3);
    __hip_bfloat16* xwr  = (__hip_bfloat16*)S(0);   // xw_raw (pre-mix)
    __hip_bfloat16* rw0  = (__hip_bfloat16*)S(1);
    __hip_bfloat16* xwT  = (__hip_bfloat16*)S(2);   // xg dead
    __hip_bfloat16* T1   = (__hip_bfloat16*)S(3);   // rg dead
    __hip_bfloat16* xg1  = (__hip_bfloat16*)S(2);   // xwT dead after T1 gemm
    __hip_bfloat16* rg1  = (__hip_bfloat16*)S(4);
    __hip_bfloat16* orw  = (__hip_bfloat16*)S(0);   // xwr dead after dual1
    __hip_bfloat16* rw1  = (__hip_bfloat16*)S(1);

    __hip_bfloat16* WresT = WT;             // 64x64
    __hip_bfloat16* Wg0T  = WT + 4096;      // 256x64
    __hip_bfloat16* Wrg0T = WT + 20480;     // 256x64
    __hip_bfloat16* Wc0T  = WT + 36864;     // 256x256 (coeff-scaled Wwo0^T)
    __hip_bfloat16* Wrw0T = WT + 102400;    // 256x64
    __hip_bfloat16* Wg1T  = WT + 118784;    // 256x256
    __hip_bfloat16* Wrg1T = WT + 184320;    // 256x64
    __hip_bfloat16* Wc1T  = WT + 200704;    // 64x256 (coeff-scaled Wwo1^T)
    __hip_bfloat16* Wrw1T = WT + 217088;    // 64x64

    const dim3 blk(256);
    const float invH = 1.0f / ((float)BNR * HH);
    const float invD = 1.0f / ((float)BNR * DOUT);

    // ---- prep: conversions, coeffs, folded weights, crow ----
    hipLaunchKernelGGL(coeff_k, dim3(1), dim3(256), 0, stream, logits0, gumb0, Wnl0, c0);
    hipLaunchKernelGGL(coeff_k, dim3(1), dim3(256), 0, stream, logits1, gumb1, Wnl1, c1);
    hipLaunchKernelGGL(cvt_k, dim3(2048), blk, 0, stream, x, (unsigned short*)xbf, (long)BNR * DIN / 4);
    hipLaunchKernelGGL(cvt_k, dim3(256), blk, 0, stream, adj, (unsigned short*)adjb, (long)NN * NN / 4);
    hipLaunchKernelGGL(tcvt_k, dim3(1, 8, 128), blk, 0, stream, x, (unsigned short*)xT, NN, DIN, (long)NN * DIN);

    WTArgs wa;
    wa.src[0] = Wres; wa.dst[0] = (unsigned short*)WresT; wa.cs[0] = nullptr; wa.R[0] = 64;  wa.C[0] = 64;
    wa.src[1] = Wg0;  wa.dst[1] = (unsigned short*)Wg0T;  wa.cs[1] = nullptr; wa.R[1] = 64;  wa.C[1] = 256;
    wa.src[2] = Wrg0; wa.dst[2] = (unsigned short*)Wrg0T; wa.cs[2] = nullptr; wa.R[2] = 64;  wa.C[2] = 256;
    wa.src[3] = Wwo0; wa.dst[3] = (unsigned short*)Wc0T;  wa.cs[3] = c0;      wa.R[3] = 256; wa.C[3] = 256;
    wa.src[4] = Wrw0; wa.dst[4] = (unsigned short*)Wrw0T; wa.cs[4] = nullptr; wa.R[4] = 64;  wa.C[4] = 256;
    wa.src[5] = Wg1;  wa.dst[5] = (unsigned short*)Wg1T;  wa.cs[5] = nullptr; wa.R[5] = 256; wa.C[5] = 256;
    wa.src[6] = Wrg1; wa.dst[6] = (unsigned short*)Wrg1T; wa.cs[6] = nullptr; wa.R[6] = 64;  wa.C[6] = 256;
    wa.src[7] = Wwo1; wa.dst[7] = (unsigned short*)Wc1T;  wa.cs[7] = c1;      wa.R[7] = 256; wa.C[7] = 64;
    wa.src[8] = Wrw1; wa.dst[8] = (unsigned short*)Wrw1T; wa.cs[8] = nullptr; wa.R[8] = 64;  wa.C[8] = 64;
    hipLaunchKernelGGL(tcvt_w_k, dim3(16, 9), blk, 0, stream, wa);

    hipLaunchKernelGGL(crow_k, dim3(1), dim3(256), 0, stream, Wwo0, bnl0, bwo0, crow0, HH, HH);
    hipLaunchKernelGGL(crow_k, dim3(1), dim3(64), 0, stream, Wwo1, bnl1, bwo1, crow1, HH, DOUT);

    // res = x @ Wres + bres
    hipLaunchKernelGGL((gemm_bt_k<128, 64, 4, 2>), dim3(1, BNR / 128, 1), blk, 0, stream,
                       xbf, WresT, bres, Rbf, BNR, DOUT, DIN, 0, 0, 0);

    // T0 = adj @ x (batched)
    hipLaunchKernelGGL((gemm_bt_k<128, 64, 4, 2>), dim3(1, 4, BB), blk, 0, stream,
                       adjb, xT, nullptr, T0, NN, DIN, NN, 0, (long)DIN * NN, (long)NN * DIN);

    // dual0: xg = T0@Wg0+bg0 ; rg = Rbf@Wrg0+brg0 (+diff)
    hipLaunchKernelGGL((dual_k<64, 128, 2, 4>), dim3(2, BNR / 64), blk, 0, stream,
                       T0, Wg0T, bg0, Rbf, Wrg0T, brg0, xg, rg, partial, BNR, HH, DIN, DOUT);
    hipLaunchKernelGGL(diff_final_k, dim3(1), blk, 0, stream, partial, 2048, th_s + 0, invH);

    // triple_w0: xwr = th0*(xg@Wc0)+om0*(rg@Wc0)+crow0+mix(xg,rg) ; rw0 = Rbf@Wrw0+brw0
    hipLaunchKernelGGL((triple_k<64, 128, 2, 4, true>), dim3(2, BNR / 64), blk, 0, stream,
                       xg, rg, Rbf, Wc0T, Wrw0T, th_s + 0, crow0, brw0,
                       xwr, rw0, partial, BNR, HH, HH, DOUT);
    hipLaunchKernelGGL(diff_final_k, dim3(1), blk, 0, stream, partial, 2048, th_s + 1, invH);

    // xwT = transpose(mix(xwr, rw0))
    hipLaunchKernelGGL(mixT_k, dim3(4, 8, BB), blk, 0, stream,
                       (const unsigned short*)xwr, (const unsigned short*)rw0, th_s + 1,
                       (unsigned short*)xwT);

    // T1 = adj @ xw (batched)
    hipLaunchKernelGGL((gemm_bt_k<128, 128, 4, 4>), dim3(2, 4, BB), blk, 0, stream,
                       adjb, xwT, nullptr, T1, NN, HH, NN, 0, (long)HH * NN, (long)NN * HH);

    // dual1: xg1 = T1@Wg1+bg1 + mix(xwr,rw0) ; rg1 = Rbf@Wrg1+brg1 (+diff)
    hipLaunchKernelGGL((dualmix_k<64, 128, 2, 4>), dim3(2, BNR / 64), blk, 0, stream,
                       T1, Wg1T, bg1, Rbf, Wrg1T, brg1,
                       xwr, rw0, th_s + 1, xg1, rg1, partial, BNR, HH, HH, DOUT);
    hipLaunchKernelGGL(diff_final_k, dim3(1), blk, 0, stream, partial, 2048, th_s + 2, invH);

    // triple_out: orw = th2*(xg1@Wc1)+om2*(rg1@Wc1)+crow1 ; rw1 = Rbf@Wrw1+brw1
    hipLaunchKernelGGL((triple_k<64, 64, 2, 2, false>), dim3(1, BNR / 64), blk, 0, stream,
                       xg1, rg1, Rbf, Wc1T, Wrw1T, th_s + 2, crow1, brw1,
                       orw, rw1, partial, BNR, DOUT, HH, DIN);
    hipLaunchKernelGGL(diff_final_k, dim3(1), blk, 0, stream, partial, 1024, th_s + 3, invD);

    // final mix -> fp32 out
    hipLaunchKernelGGL(mixfinal_k, dim3(2048), blk, 0, stream,
                       (const unsigned short*)orw, (const unsigned short*)rw1, th_s + 3,
                       out, (long)BNR * DOUT / 4);
}

// Round 6
// 256.202 us; speedup vs baseline: 1.4117x; 1.4117x over previous
//
#include <hip/hip_runtime.h>
#include <hip/hip_bf16.h>
#include <math.h>

#define BB   128
#define NN   512
#define DIN  64
#define HH   256
#define DOUT 64
#define BNR  (BB * NN)          // 65536 rows

typedef float  f32x4  __attribute__((ext_vector_type(4)));
typedef __bf16 bf16x8 __attribute__((ext_vector_type(8)));

#define GLP(p)  ((const __attribute__((address_space(1))) void*)(p))
#define LDSP(p) ((__attribute__((address_space(3))) void*)(p))

// Haar/db1 'zero' DWT patterns, levels 1..3, FULL_LEN=8
__constant__ float PAT[3][8] = {
    {0.70710678f, 0.70710678f, 0.f, 0.f, 0.f, 0.f, 0.f, 0.f},
    {0.5f,        0.70710678f, 0.f, 0.5f, 0.f, 0.f, 0.f, 0.f},
    {0.35355339f, 0.70710678f, 0.f, 0.f, 0.f, 0.5f, 0.f, 0.35355339f}
};

__device__ __forceinline__ unsigned short f2bfu(float x) {
    __hip_bfloat16 b = __float2bfloat16(x);
    unsigned short u;
    __builtin_memcpy(&u, &b, 2);
    return u;
}
__device__ __forceinline__ float bf2f(unsigned short u) {
    unsigned int v = ((unsigned int)u) << 16;
    float f;
    __builtin_memcpy(&f, &v, 4);
    return f;
}

// ---------------------------------------------------------------------------
// Coalesced bf16 tile write via LDS staging (verified round 4).
// ---------------------------------------------------------------------------
template<int BM, int BN, int FM, int FN>
__device__ __forceinline__ void write_tile(char* lds, f32x4 (&a)[FM][FN],
                                           __hip_bfloat16* __restrict__ C,
                                           long base, int N, int tid)
{
    const int wave = tid >> 6;
    const int lane = tid & 63;
    const int wm = wave >> 1, wn = wave & 1;
    const int lc = lane & 15;
    const int lr4 = (lane >> 4) << 2;
    __syncthreads();
    #pragma unroll
    for (int j = 0; j < FN; ++j) {
        int colb = (wn * (FN * 16) + j * 16 + lc) * 2;
        #pragma unroll
        for (int i = 0; i < FM; ++i) {
            int row0 = wm * (FM * 16) + i * 16 + lr4;
            #pragma unroll
            for (int r = 0; r < 4; ++r) {
                int row = row0 + r;
                *reinterpret_cast<unsigned short*>(
                    lds + row * (BN * 2) + (colb ^ (((row >> 2) & 3) << 5))) =
                    f2bfu(a[i][j][r]);
            }
        }
    }
    __syncthreads();
    const int TPR = BN / 8;          // threads per row (16B each)
    const int RPP = 256 / TPR;       // rows per pass
    #pragma unroll
    for (int p = 0; p < BM / RPP; ++p) {
        int row = p * RPP + tid / TPR;
        int cb = (tid % TPR) * 16;
        int pb = cb ^ (((row >> 2) & 3) << 5);
        uint4 v = *reinterpret_cast<const uint4*>(lds + row * (BN * 2) + pb);
        *reinterpret_cast<uint4*>(reinterpret_cast<char*>(C + base + (long)row * N) + cb) = v;
    }
}

// ---------------------------------------------------------------------------
// fp32 -> bf16 convert
// ---------------------------------------------------------------------------
__global__ __launch_bounds__(256) void cvt_k(const float* __restrict__ in,
                                             unsigned short* __restrict__ out, long n4)
{
    long gid = (long)blockIdx.x * 256 + threadIdx.x;
    long stride = (long)gridDim.x * 256;
    for (long i = gid; i < n4; i += stride) {
        float4 v = reinterpret_cast<const float4*>(in)[i];
        ushort4 u;
        u.x = f2bfu(v.x); u.y = f2bfu(v.y); u.z = f2bfu(v.z); u.w = f2bfu(v.w);
        reinterpret_cast<ushort4*>(out)[i] = u;
    }
}

// ---------------------------------------------------------------------------
// transpose-convert fp32 (R,C) -> bf16 (C,R) with optional per-source-row scale
// ---------------------------------------------------------------------------
__device__ __forceinline__ void tcvt_body(const float* __restrict__ in,
                                          unsigned short* __restrict__ out,
                                          const float* __restrict__ cs,
                                          int R, int C, int r0, int c0)
{
    __shared__ float t[64][65];
    int tr = threadIdx.x >> 6;
    int tc = threadIdx.x & 63;
    #pragma unroll
    for (int i = 0; i < 16; ++i) {
        int r = i * 4 + tr;
        t[r][tc] = in[(long)(r0 + r) * C + c0 + tc];
    }
    __syncthreads();
    float sc = cs ? cs[r0 + tc] : 1.0f;
    #pragma unroll
    for (int i = 0; i < 16; ++i) {
        int r = i * 4 + tr;
        out[(long)(c0 + r) * R + r0 + tc] = f2bfu(t[tc][r] * sc);
    }
}

__global__ __launch_bounds__(256) void tcvt_k(const float* __restrict__ in,
                                              unsigned short* __restrict__ out,
                                              int R, int C, long sz)
{
    long base = (long)blockIdx.z * sz;
    tcvt_body(in + base, out + base, nullptr, R, C, blockIdx.y * 64, blockIdx.x * 64);
}

struct WTArgs {
    const float* src[9];
    unsigned short* dst[9];
    const float* cs[9];
    int R[9], C[9];
};
__global__ __launch_bounds__(256) void tcvt_w_k(WTArgs a)
{
    int wgt = blockIdx.y;
    int R = a.R[wgt], C = a.C[wgt];
    int tilesX = C >> 6;
    int tiles = (R >> 6) * tilesX;
    int t = blockIdx.x;
    if (t >= tiles) return;
    tcvt_body(a.src[wgt], a.dst[wgt], a.cs[wgt], R, C, (t / tilesX) * 64, (t % tilesX) * 64);
}

// ---------------------------------------------------------------------------
// wavelet coeff
// ---------------------------------------------------------------------------
__global__ void coeff_k(const float* __restrict__ logits, const float* __restrict__ gumb,
                        const float* __restrict__ Wnl, float* __restrict__ coeff)
{
    int f = threadIdx.x;
    float l0 = logits[0] + gumb[f * 3 + 0];
    float l1 = logits[1] + gumb[f * 3 + 1];
    float l2 = logits[2] + gumb[f * 3 + 2];
    int bl = 0;
    float bv = l0;
    if (l1 > bv) { bv = l1; bl = 1; }
    if (l2 > bv) { bv = l2; bl = 2; }
    float s = 0.f;
    #pragma unroll
    for (int t = 0; t < 8; ++t) s += Wnl[f * 8 + t] * PAT[bl][t];
    coeff[f] = s;
}

// crow[n] = bias[n] + sum_k bnl[k] * W[k*N+n]
// PARALLEL version: one block per column n, 256 threads over k, tree reduce.
// (round-5 single-block version was 66 us: serial dependent-load chain)
__global__ __launch_bounds__(256) void crow_k(const float* __restrict__ W,
                                              const float* __restrict__ bnl,
                                              const float* __restrict__ bias,
                                              float* __restrict__ out,
                                              int K, int N)
{
    int n = blockIdx.x;
    int k = threadIdx.x;
    float s = (k < K) ? bnl[k] * W[(long)k * N + n] : 0.f;
    __shared__ float sm[256];
    sm[threadIdx.x] = s;
    __syncthreads();
    for (int o = 128; o > 0; o >>= 1) {
        if (threadIdx.x < o) sm[threadIdx.x] += sm[threadIdx.x + o];
        __syncthreads();
    }
    if (threadIdx.x == 0) out[n] = bias[n] + sm[0];
}

// ---------------------------------------------------------------------------
// Single MFMA bf16 GEMM (bf16 out, coalesced epilogue)
// ---------------------------------------------------------------------------
template<int BM, int BN, int FM, int FN>
__global__ __launch_bounds__(256) void gemm_bt_k(
    const __hip_bfloat16* __restrict__ A, const __hip_bfloat16* __restrict__ Bt,
    const float* __restrict__ bias, __hip_bfloat16* __restrict__ Cb,
    int M, int N, int K, long sA, long sB, long sC)
{
    __shared__ __attribute__((aligned(128))) char lds[(BM + BN) * 128];
    char* AsB = lds;
    char* BsB = lds + BM * 128;

    const long bz = blockIdx.z;
    const __hip_bfloat16* Ab = A + bz * sA;
    const __hip_bfloat16* Bb = Bt + bz * sB;

    const int m0 = blockIdx.y * BM;
    const int n0 = blockIdx.x * BN;
    const int tid  = threadIdx.x;
    const int wave = tid >> 6;
    const int lane = tid & 63;
    const int wm = wave >> 1, wn = wave & 1;

    const int NCH = (BM + BN) / 32;
    const int lr = lane >> 3;
    const int ls = lane & 7;

    f32x4 acc[FM][FN];
    #pragma unroll
    for (int i = 0; i < FM; ++i)
        #pragma unroll
        for (int j = 0; j < FN; ++j)
            acc[i][j] = (f32x4){0.f, 0.f, 0.f, 0.f};

    for (int k0 = 0; k0 < K; k0 += 64) {
        #pragma unroll
        for (int cc = 0; cc < NCH; ++cc) {
            int c = wave * NCH + cc;
            const __hip_bfloat16* src;
            char* ldsb;
            if (c < BM / 8) {
                int r = c * 8 + lr;
                ldsb = AsB + c * 1024;
                src = Ab + ((long)(m0 + r) * K + k0 + ((ls ^ (r & 7)) << 3));
            } else {
                int c2 = c - BM / 8;
                int r = c2 * 8 + lr;
                ldsb = BsB + c2 * 1024;
                src = Bb + ((long)(n0 + r) * K + k0 + ((ls ^ (r & 7)) << 3));
            }
            __builtin_amdgcn_global_load_lds(GLP(src), LDSP(ldsb), 16, 0, 0);
        }
        __syncthreads();

        #pragma unroll
        for (int ksl = 0; ksl < 2; ++ksl) {
            bf16x8 af[FM], bfr[FN];
            #pragma unroll
            for (int i = 0; i < FM; ++i) {
                int row = wm * (FM * 16) + i * 16 + (lane & 15);
                int off = (ksl * 64 + ((lane >> 4) << 4)) ^ ((row & 7) << 4);
                af[i] = *reinterpret_cast<const bf16x8*>(AsB + row * 128 + off);
            }
            #pragma unroll
            for (int j = 0; j < FN; ++j) {
                int row = wn * (FN * 16) + j * 16 + (lane & 15);
                int off = (ksl * 64 + ((lane >> 4) << 4)) ^ ((row & 7) << 4);
                bfr[j] = *reinterpret_cast<const bf16x8*>(BsB + row * 128 + off);
            }
            #pragma unroll
            for (int i = 0; i < FM; ++i)
                #pragma unroll
                for (int j = 0; j < FN; ++j)
                    acc[i][j] = __builtin_amdgcn_mfma_f32_16x16x32_bf16(
                        af[i], bfr[j], acc[i][j], 0, 0, 0);
        }
        __syncthreads();
    }

    const int lc = lane & 15;
    #pragma unroll
    for (int j = 0; j < FN; ++j) {
        int col = n0 + wn * (FN * 16) + j * 16 + lc;
        float bv = bias ? bias[col] : 0.0f;
        #pragma unroll
        for (int i = 0; i < FM; ++i)
            #pragma unroll
            for (int r = 0; r < 4; ++r)
                acc[i][j][r] += bv;
    }
    write_tile<BM, BN, FM, FN>(lds, acc, Cb, bz * sC + (long)m0 * N + n0, N, tid);
}

// ---------------------------------------------------------------------------
// Dual MFMA GEMM + in-register diff
// ---------------------------------------------------------------------------
template<int BM, int BN, int FM, int FN>
__global__ __launch_bounds__(256) void dual_k(
    const __hip_bfloat16* __restrict__ A1, const __hip_bfloat16* __restrict__ B1t,
    const float* __restrict__ bias1,
    const __hip_bfloat16* __restrict__ A2, const __hip_bfloat16* __restrict__ B2t,
    const float* __restrict__ bias2,
    __hip_bfloat16* __restrict__ C1, __hip_bfloat16* __restrict__ C2,
    float* __restrict__ partial,
    int M, int N, int K1, int K2)
{
    __shared__ __attribute__((aligned(128))) char lds[(BM + BN) * 128];
    char* AsB = lds;
    char* BsB = lds + BM * 128;

    const int m0 = blockIdx.y * BM;
    const int n0 = blockIdx.x * BN;
    const int tid  = threadIdx.x;
    const int wave = tid >> 6;
    const int lane = tid & 63;
    const int wm = wave >> 1, wn = wave & 1;

    const int NCH = (BM + BN) / 32;
    const int lr = lane >> 3;
    const int ls = lane & 7;

    f32x4 acc[2][FM][FN];
    #pragma unroll
    for (int p = 0; p < 2; ++p)
        #pragma unroll
        for (int i = 0; i < FM; ++i)
            #pragma unroll
            for (int j = 0; j < FN; ++j)
                acc[p][i][j] = (f32x4){0.f, 0.f, 0.f, 0.f};

    #pragma unroll
    for (int ph = 0; ph < 2; ++ph) {
        const __hip_bfloat16* Ab = ph ? A2 : A1;
        const __hip_bfloat16* Bb = ph ? B2t : B1t;
        const int K = ph ? K2 : K1;

        for (int k0 = 0; k0 < K; k0 += 64) {
            #pragma unroll
            for (int cc = 0; cc < NCH; ++cc) {
                int c = wave * NCH + cc;
                const __hip_bfloat16* src;
                char* ldsb;
                if (c < BM / 8) {
                    int r = c * 8 + lr;
                    ldsb = AsB + c * 1024;
                    src = Ab + ((long)(m0 + r) * K + k0 + ((ls ^ (r & 7)) << 3));
                } else {
                    int c2 = c - BM / 8;
                    int r = c2 * 8 + lr;
                    ldsb = BsB + c2 * 1024;
                    src = Bb + ((long)(n0 + r) * K + k0 + ((ls ^ (r & 7)) << 3));
                }
                __builtin_amdgcn_global_load_lds(GLP(src), LDSP(ldsb), 16, 0, 0);
            }
            __syncthreads();

            #pragma unroll
            for (int ksl = 0; ksl < 2; ++ksl) {
                bf16x8 af[FM], bfr[FN];
                #pragma unroll
                for (int i = 0; i < FM; ++i) {
                    int row = wm * (FM * 16) + i * 16 + (lane & 15);
                    int off = (ksl * 64 + ((lane >> 4) << 4)) ^ ((row & 7) << 4);
                    af[i] = *reinterpret_cast<const bf16x8*>(AsB + row * 128 + off);
                }
                #pragma unroll
                for (int j = 0; j < FN; ++j) {
                    int row = wn * (FN * 16) + j * 16 + (lane & 15);
                    int off = (ksl * 64 + ((lane >> 4) << 4)) ^ ((row & 7) << 4);
                    bfr[j] = *reinterpret_cast<const bf16x8*>(BsB + row * 128 + off);
                }
                #pragma unroll
                for (int i = 0; i < FM; ++i)
                    #pragma unroll
                    for (int j = 0; j < FN; ++j)
                        acc[ph][i][j] = __builtin_amdgcn_mfma_f32_16x16x32_bf16(
                            af[i], bfr[j], acc[ph][i][j], 0, 0, 0);
            }
            __syncthreads();
        }
    }

    const int lc  = lane & 15;
    float dsum = 0.f;
    #pragma unroll
    for (int j = 0; j < FN; ++j) {
        int col = n0 + wn * (FN * 16) + j * 16 + lc;
        float b1 = bias1 ? bias1[col] : 0.0f;
        float b2 = bias2 ? bias2[col] : 0.0f;
        #pragma unroll
        for (int i = 0; i < FM; ++i)
            #pragma unroll
            for (int r = 0; r < 4; ++r) {
                float v1 = acc[0][i][j][r] + b1;
                float v2 = acc[1][i][j][r] + b2;
                acc[0][i][j][r] = v1;
                acc[1][i][j][r] = v2;
                float d = v1 - v2;
                dsum += d * d;
            }
    }

    float* red = (float*)lds;
    red[tid] = dsum;
    __syncthreads();
    for (int o = 128; o > 0; o >>= 1) {
        if (tid < o) red[tid] += red[tid + o];
        __syncthreads();
    }
    if (tid == 0) partial[blockIdx.y * gridDim.x + blockIdx.x] = red[0];

    write_tile<BM, BN, FM, FN>(lds, acc[0], C1, (long)m0 * N + n0, N, tid);
    write_tile<BM, BN, FM, FN>(lds, acc[1], C2, (long)m0 * N + n0, N, tid);
}

// ---------------------------------------------------------------------------
// Triple MFMA GEMM (wavelet layer fused) — as round 5.
// ---------------------------------------------------------------------------
template<int BM, int BN, int FM, int FN, bool MIX>
__global__ __launch_bounds__(256) void triple_k(
    const __hip_bfloat16* __restrict__ A0, const __hip_bfloat16* __restrict__ A1,
    const __hip_bfloat16* __restrict__ A2,
    const __hip_bfloat16* __restrict__ B01t, const __hip_bfloat16* __restrict__ B2t,
    const float* __restrict__ th_p, const float* __restrict__ crow,
    const float* __restrict__ bias2,
    __hip_bfloat16* __restrict__ C1, __hip_bfloat16* __restrict__ C2,
    float* __restrict__ partial,
    int M, int N, int K01, int K2)
{
    __shared__ __attribute__((aligned(128))) char lds[(BM + BN) * 128];
    char* AsB = lds;
    char* BsB = lds + BM * 128;

    const float th = th_p[0];
    const float om = 1.f - th;

    const int m0 = blockIdx.y * BM;
    const int n0 = blockIdx.x * BN;
    const int tid  = threadIdx.x;
    const int wave = tid >> 6;
    const int lane = tid & 63;
    const int wm = wave >> 1, wn = wave & 1;

    const int NCH = (BM + BN) / 32;
    const int lr = lane >> 3;
    const int ls = lane & 7;
    const int lc = lane & 15;
    const int lr4 = (lane >> 4) << 2;

    const int kgrab  = n0 + ((wn * FN * 16) & ~63);
    const int cgbase = wn * FN * 16 - (kgrab - n0);

    f32x4 acc[3][FM][FN];
    #pragma unroll
    for (int p = 0; p < 3; ++p)
        #pragma unroll
        for (int i = 0; i < FM; ++i)
            #pragma unroll
            for (int j = 0; j < FN; ++j)
                acc[p][i][j] = (f32x4){0.f, 0.f, 0.f, 0.f};

    unsigned int mixu[2][FM][FN][2];

    #pragma unroll
    for (int ph = 0; ph < 3; ++ph) {
        const __hip_bfloat16* Ab = (ph == 0) ? A0 : (ph == 1 ? A1 : A2);
        const __hip_bfloat16* Bb = (ph == 2) ? B2t : B01t;
        const int K = (ph == 2) ? K2 : K01;

        for (int k0 = 0; k0 < K; k0 += 64) {
            #pragma unroll
            for (int cc = 0; cc < NCH; ++cc) {
                int c = wave * NCH + cc;
                const __hip_bfloat16* src;
                char* ldsb;
                if (c < BM / 8) {
                    int r = c * 8 + lr;
                    ldsb = AsB + c * 1024;
                    src = Ab + ((long)(m0 + r) * K + k0 + ((ls ^ (r & 7)) << 3));
                } else {
                    int c2 = c - BM / 8;
                    int r = c2 * 8 + lr;
                    ldsb = BsB + c2 * 1024;
                    src = Bb + ((long)(n0 + r) * K + k0 + ((ls ^ (r & 7)) << 3));
                }
                __builtin_amdgcn_global_load_lds(GLP(src), LDSP(ldsb), 16, 0, 0);
            }
            __syncthreads();

            #pragma unroll
            for (int ksl = 0; ksl < 2; ++ksl) {
                bf16x8 af[FM], bfr[FN];
                #pragma unroll
                for (int i = 0; i < FM; ++i) {
                    int row = wm * (FM * 16) + i * 16 + lc;
                    int off = (ksl * 64 + ((lane >> 4) << 4)) ^ ((row & 7) << 4);
                    af[i] = *reinterpret_cast<const bf16x8*>(AsB + row * 128 + off);
                }
                #pragma unroll
                for (int j = 0; j < FN; ++j) {
                    int row = wn * (FN * 16) + j * 16 + lc;
                    int off = (ksl * 64 + ((lane >> 4) << 4)) ^ ((row & 7) << 4);
                    bfr[j] = *reinterpret_cast<const bf16x8*>(BsB + row * 128 + off);
                }
                #pragma unroll
                for (int i = 0; i < FM; ++i)
                    #pragma unroll
                    for (int j = 0; j < FN; ++j)
                        acc[ph][i][j] = __builtin_amdgcn_mfma_f32_16x16x32_bf16(
                            af[i], bfr[j], acc[ph][i][j], 0, 0, 0);
            }

            if constexpr (MIX) {
                if (ph < 2 && k0 == kgrab) {
                    #pragma unroll
                    for (int i = 0; i < FM; ++i) {
                        #pragma unroll
                        for (int j = 0; j < FN; ++j) {
                            int colk2 = (cgbase + j * 16 + lc) * 2;
                            #pragma unroll
                            for (int rh = 0; rh < 2; ++rh) {
                                int row0 = wm * (FM * 16) + i * 16 + lr4 + rh * 2;
                                unsigned short g0 = *reinterpret_cast<const unsigned short*>(
                                    AsB + row0 * 128 + (colk2 ^ ((row0 & 7) << 4)));
                                int row1 = row0 + 1;
                                unsigned short g1 = *reinterpret_cast<const unsigned short*>(
                                    AsB + row1 * 128 + (colk2 ^ ((row1 & 7) << 4)));
                                mixu[ph][i][j][rh] = (unsigned int)g0 | ((unsigned int)g1 << 16);
                            }
                        }
                    }
                }
            }
            __syncthreads();
        }
    }

    float dsum = 0.f;
    #pragma unroll
    for (int j = 0; j < FN; ++j) {
        int col = n0 + wn * (FN * 16) + j * 16 + lc;
        float cr = crow[col];
        float b2 = bias2 ? bias2[col] : 0.0f;
        #pragma unroll
        for (int i = 0; i < FM; ++i)
            #pragma unroll
            for (int r = 0; r < 4; ++r) {
                float v1 = th * acc[0][i][j][r] + om * acc[1][i][j][r] + cr;
                if constexpr (MIX) {
                    unsigned int u0 = mixu[0][i][j][r >> 1];
                    unsigned int u1 = mixu[1][i][j][r >> 1];
                    unsigned short a = (r & 1) ? (unsigned short)(u0 >> 16) : (unsigned short)u0;
                    unsigned short b = (r & 1) ? (unsigned short)(u1 >> 16) : (unsigned short)u1;
                    v1 += th * bf2f(a) + om * bf2f(b);
                }
                float v2 = acc[2][i][j][r] + b2;
                acc[0][i][j][r] = v1;
                acc[2][i][j][r] = v2;
                float d = v1 - v2;
                dsum += d * d;
            }
    }

    float* red = (float*)lds;
    red[tid] = dsum;
    __syncthreads();
    for (int o = 128; o > 0; o >>= 1) {
        if (tid < o) red[tid] += red[tid + o];
        __syncthreads();
    }
    if (tid == 0) partial[blockIdx.y * gridDim.x + blockIdx.x] = red[0];

    write_tile<BM, BN, FM, FN>(lds, acc[0], C1, (long)m0 * N + n0, N, tid);
    write_tile<BM, BN, FM, FN>(lds, acc[2], C2, (long)m0 * N + n0, N, tid);
}

// ---------------------------------------------------------------------------
// Dual GEMM with global mix-residual on C1 (for xg1) — as round 5.
// ---------------------------------------------------------------------------
template<int BM, int BN, int FM, int FN>
__global__ __launch_bounds__(256) void dualmix_k(
    const __hip_bfloat16* __restrict__ A1, const __hip_bfloat16* __restrict__ B1t,
    const float* __restrict__ bias1,
    const __hip_bfloat16* __restrict__ A2, const __hip_bfloat16* __restrict__ B2t,
    const float* __restrict__ bias2,
    const __hip_bfloat16* __restrict__ mixA, const __hip_bfloat16* __restrict__ mixB,
    const float* __restrict__ th_p,
    __hip_bfloat16* __restrict__ C1, __hip_bfloat16* __restrict__ C2,
    float* __restrict__ partial,
    int M, int N, int K1, int K2)
{
    __shared__ __attribute__((aligned(128))) char lds[BM * BN * 4];
    char* AsB = lds;
    char* BsB = lds + BM * 128;

    const float th = th_p[0];
    const float om = 1.f - th;

    const int m0 = blockIdx.y * BM;
    const int n0 = blockIdx.x * BN;
    const int tid  = threadIdx.x;
    const int wave = tid >> 6;
    const int lane = tid & 63;
    const int wm = wave >> 1, wn = wave & 1;

    const int NCH = (BM + BN) / 32;
    const int lr = lane >> 3;
    const int ls = lane & 7;

    f32x4 acc[2][FM][FN];
    #pragma unroll
    for (int p = 0; p < 2; ++p)
        #pragma unroll
        for (int i = 0; i < FM; ++i)
            #pragma unroll
            for (int j = 0; j < FN; ++j)
                acc[p][i][j] = (f32x4){0.f, 0.f, 0.f, 0.f};

    #pragma unroll
    for (int ph = 0; ph < 2; ++ph) {
        const __hip_bfloat16* Ab = ph ? A2 : A1;
        const __hip_bfloat16* Bb = ph ? B2t : B1t;
        const int K = ph ? K2 : K1;

        for (int k0 = 0; k0 < K; k0 += 64) {
            #pragma unroll
            for (int cc = 0; cc < NCH; ++cc) {
                int c = wave * NCH + cc;
                const __hip_bfloat16* src;
                char* ldsb;
                if (c < BM / 8) {
                    int r = c * 8 + lr;
                    ldsb = AsB + c * 1024;
                    src = Ab + ((long)(m0 + r) * K + k0 + ((ls ^ (r & 7)) << 3));
                } else {
                    int c2 = c - BM / 8;
                    int r = c2 * 8 + lr;
                    ldsb = BsB + c2 * 1024;
                    src = Bb + ((long)(n0 + r) * K + k0 + ((ls ^ (r & 7)) << 3));
                }
                __builtin_amdgcn_global_load_lds(GLP(src), LDSP(ldsb), 16, 0, 0);
            }
            __syncthreads();

            #pragma unroll
            for (int ksl = 0; ksl < 2; ++ksl) {
                bf16x8 af[FM], bfr[FN];
                #pragma unroll
                for (int i = 0; i < FM; ++i) {
                    int row = wm * (FM * 16) + i * 16 + (lane & 15);
                    int off = (ksl * 64 + ((lane >> 4) << 4)) ^ ((row & 7) << 4);
                    af[i] = *reinterpret_cast<const bf16x8*>(AsB + row * 128 + off);
                }
                #pragma unroll
                for (int j = 0; j < FN; ++j) {
                    int row = wn * (FN * 16) + j * 16 + (lane & 15);
                    int off = (ksl * 64 + ((lane >> 4) << 4)) ^ ((row & 7) << 4);
                    bfr[j] = *reinterpret_cast<const bf16x8*>(BsB + row * 128 + off);
                }
                #pragma unroll
                for (int i = 0; i < FM; ++i)
                    #pragma unroll
                    for (int j = 0; j < FN; ++j)
                        acc[ph][i][j] = __builtin_amdgcn_mfma_f32_16x16x32_bf16(
                            af[i], bfr[j], acc[ph][i][j], 0, 0, 0);
            }
            __syncthreads();
        }
    }

    const int lc  = lane & 15;
    const int lr4 = (lane >> 4) << 2;
    float* ldsf = (float*)lds;
    const int TPR = BN / 8;
    const int RPP = 256 / TPR;
    const int NP  = BM / RPP;

    #pragma unroll
    for (int j = 0; j < FN; ++j) {
        int col = n0 + wn * (FN * 16) + j * 16 + lc;
        float b1 = bias1 ? bias1[col] : 0.0f;
        #pragma unroll
        for (int i = 0; i < FM; ++i) {
            int rowb = wm * (FM * 16) + i * 16 + lr4;
            #pragma unroll
            for (int r = 0; r < 4; ++r)
                ldsf[(rowb + r) * BN + wn * (FN * 16) + j * 16 + lc] = acc[0][i][j][r] + b1;
        }
    }
    __syncthreads();

    float v1k[NP][8];
    float dsum = 0.f;
    #pragma unroll
    for (int p = 0; p < NP; ++p) {
        int row = p * RPP + tid / TPR;
        int cole = (tid % TPR) * 8;
        long gidx = (long)(m0 + row) * N + n0 + cole;
        uint4 ma = *reinterpret_cast<const uint4*>(mixA + gidx);
        uint4 mb = *reinterpret_cast<const uint4*>(mixB + gidx);
        unsigned int outp[4];
        #pragma unroll
        for (int q = 0; q < 4; ++q) {
            unsigned int wa = (&ma.x)[q];
            unsigned int wb = (&mb.x)[q];
            float v0 = ldsf[row * BN + cole + q * 2]
                     + th * bf2f((unsigned short)wa) + om * bf2f((unsigned short)wb);
            float v1 = ldsf[row * BN + cole + q * 2 + 1]
                     + th * bf2f((unsigned short)(wa >> 16)) + om * bf2f((unsigned short)(wb >> 16));
            v1k[p][q * 2] = v0;
            v1k[p][q * 2 + 1] = v1;
            outp[q] = (unsigned int)f2bfu(v0) | ((unsigned int)f2bfu(v1) << 16);
        }
        *reinterpret_cast<uint4*>(C1 + gidx) = make_uint4(outp[0], outp[1], outp[2], outp[3]);
    }
    __syncthreads();

    #pragma unroll
    for (int j = 0; j < FN; ++j) {
        int col = n0 + wn * (FN * 16) + j * 16 + lc;
        float b2 = bias2 ? bias2[col] : 0.0f;
        #pragma unroll
        for (int i = 0; i < FM; ++i) {
            int rowb = wm * (FM * 16) + i * 16 + lr4;
            #pragma unroll
            for (int r = 0; r < 4; ++r)
                ldsf[(rowb + r) * BN + wn * (FN * 16) + j * 16 + lc] = acc[1][i][j][r] + b2;
        }
    }
    __syncthreads();

    #pragma unroll
    for (int p = 0; p < NP; ++p) {
        int row = p * RPP + tid / TPR;
        int cole = (tid % TPR) * 8;
        long gidx = (long)(m0 + row) * N + n0 + cole;
        unsigned int outp[4];
        #pragma unroll
        for (int q = 0; q < 4; ++q) {
            float v0 = ldsf[row * BN + cole + q * 2];
            float v1 = ldsf[row * BN + cole + q * 2 + 1];
            float d0 = v1k[p][q * 2] - v0;
            float d1 = v1k[p][q * 2 + 1] - v1;
            dsum += d0 * d0 + d1 * d1;
            outp[q] = (unsigned int)f2bfu(v0) | ((unsigned int)f2bfu(v1) << 16);
        }
        *reinterpret_cast<uint4*>(C2 + gidx) = make_uint4(outp[0], outp[1], outp[2], outp[3]);
    }
    __syncthreads();

    float* red = (float*)lds;
    red[tid] = dsum;
    __syncthreads();
    for (int o = 128; o > 0; o >>= 1) {
        if (tid < o) red[tid] += red[tid + o];
        __syncthreads();
    }
    if (tid == 0) partial[blockIdx.y * gridDim.x + blockIdx.x] = red[0];
}

// ---------------------------------------------------------------------------
// th = sigmoid(sum(partial)/n)
// ---------------------------------------------------------------------------
__global__ __launch_bounds__(256) void diff_final_k(
    const float* __restrict__ partial, int np, float* __restrict__ th_out, float inv_n)
{
    float s = 0.f;
    for (int i = threadIdx.x; i < np; i += 256) s += partial[i];
    __shared__ float sm[256];
    sm[threadIdx.x] = s;
    __syncthreads();
    for (int o = 128; o > 0; o >>= 1) {
        if (threadIdx.x < o) sm[threadIdx.x] += sm[threadIdx.x + o];
        __syncthreads();
    }
    if (threadIdx.x == 0) {
        float d = sm[0] * inv_n;
        th_out[0] = 1.f / (1.f + expf(-d));
    }
}

// ---------------------------------------------------------------------------
// mix + batched transpose, writes xwT (b,H,N) — vectorized ushort4 I/O
// tile 64x64; 256 threads: 16 rows x 16x4 cols per pass, 4 passes.
// ---------------------------------------------------------------------------
__global__ __launch_bounds__(256) void mixT_k(
    const unsigned short* __restrict__ h, const unsigned short* __restrict__ r,
    const float* __restrict__ th_p, unsigned short* __restrict__ xwT)
{
    const float th = th_p[0];
    const float om = 1.f - th;
    __shared__ float t[64][65];
    const long base = (long)blockIdx.z * NN * HH;
    const int r0 = blockIdx.y * 64;
    const int c0 = blockIdx.x * 64;
    const int tr  = threadIdx.x >> 4;         // 0..15
    const int tc4 = (threadIdx.x & 15) * 4;   // 0,4,..60
    #pragma unroll
    for (int i = 0; i < 4; ++i) {
        int rr = i * 16 + tr;
        long idx = base + (long)(r0 + rr) * HH + c0 + tc4;
        ushort4 hv = *reinterpret_cast<const ushort4*>(h + idx);
        ushort4 rv = *reinterpret_cast<const ushort4*>(r + idx);
        t[rr][tc4 + 0] = th * bf2f(hv.x) + om * bf2f(rv.x);
        t[rr][tc4 + 1] = th * bf2f(hv.y) + om * bf2f(rv.y);
        t[rr][tc4 + 2] = th * bf2f(hv.z) + om * bf2f(rv.z);
        t[rr][tc4 + 3] = th * bf2f(hv.w) + om * bf2f(rv.w);
    }
    __syncthreads();
    #pragma unroll
    for (int i = 0; i < 4; ++i) {
        int cc = i * 16 + tr;                 // transposed row = original col
        ushort4 v;
        v.x = f2bfu(t[tc4 + 0][cc]);
        v.y = f2bfu(t[tc4 + 1][cc]);
        v.z = f2bfu(t[tc4 + 2][cc]);
        v.w = f2bfu(t[tc4 + 3][cc]);
        *reinterpret_cast<ushort4*>(xwT + base + (long)(c0 + cc) * NN + r0 + tc4) = v;
    }
}

// ---------------------------------------------------------------------------
// final mix: out = th*h + (1-th)*r, fp32 out
// ---------------------------------------------------------------------------
__global__ __launch_bounds__(256) void mixfinal_k(
    const unsigned short* __restrict__ h, const unsigned short* __restrict__ r,
    const float* __restrict__ th_p, float* __restrict__ out, long n4)
{
    const float th = th_p[0];
    const float om = 1.f - th;
    long gid = (long)blockIdx.x * 256 + threadIdx.x;
    long stride = (long)gridDim.x * 256;
    for (long i = gid; i < n4; i += stride) {
        ushort4 hv = reinterpret_cast<const ushort4*>(h)[i];
        ushort4 rv = reinterpret_cast<const ushort4*>(r)[i];
        float4 o;
        o.x = th * bf2f(hv.x) + om * bf2f(rv.x);
        o.y = th * bf2f(hv.y) + om * bf2f(rv.y);
        o.z = th * bf2f(hv.z) + om * bf2f(rv.z);
        o.w = th * bf2f(hv.w) + om * bf2f(rv.w);
        reinterpret_cast<float4*>(out)[i] = o;
    }
}

// ---------------------------------------------------------------------------
extern "C" void kernel_launch(void* const* d_in, const int* in_sizes, int n_in,
                              void* d_out, int out_size, void* d_ws, size_t ws_size,
                              hipStream_t stream)
{
    const float* x       = (const float*)d_in[0];
    const float* adj     = (const float*)d_in[1];
    const float* Wres    = (const float*)d_in[2];
    const float* bres    = (const float*)d_in[3];
    const float* Wg0     = (const float*)d_in[4];
    const float* bg0     = (const float*)d_in[5];
    const float* Wrg0    = (const float*)d_in[6];
    const float* brg0    = (const float*)d_in[7];
    const float* logits0 = (const float*)d_in[8];
    const float* gumb0   = (const float*)d_in[9];
    const float* Wnl0    = (const float*)d_in[10];
    const float* bnl0    = (const float*)d_in[11];
    const float* Wwo0    = (const float*)d_in[12];
    const float* bwo0    = (const float*)d_in[13];
    const float* Wrw0    = (const float*)d_in[14];
    const float* brw0    = (const float*)d_in[15];
    const float* Wg1     = (const float*)d_in[16];
    const float* bg1     = (const float*)d_in[17];
    const float* Wrg1    = (const float*)d_in[18];
    const float* brg1    = (const float*)d_in[19];
    const float* logits1 = (const float*)d_in[20];
    const float* gumb1   = (const float*)d_in[21];
    const float* Wnl1    = (const float*)d_in[22];
    const float* bnl1    = (const float*)d_in[23];
    const float* Wwo1    = (const float*)d_in[24];
    const float* bwo1    = (const float*)d_in[25];
    const float* Wrw1    = (const float*)d_in[26];
    const float* brw1    = (const float*)d_in[27];

    float* out = (float*)d_out;

    // ---- workspace ----
    char* w = (char*)d_ws;
    auto alloc = [&](long bytes) { char* p = w; w += (bytes + 255) & ~255L; return p; };
    const long SLOT = (long)BNR * HH * 2;                 // 32 MB
    char* pool = alloc(5 * SLOT);                         // 160 MB
    __hip_bfloat16* Rbf  = (__hip_bfloat16*)alloc((long)BNR * DOUT * 2); // 8 MB
    __hip_bfloat16* adjb = (__hip_bfloat16*)alloc((long)NN * NN * 2);
    __hip_bfloat16* WT   = (__hip_bfloat16*)alloc(221184L * 2);
    float* partial = (float*)alloc(4096 * 4);
    float* th_s    = (float*)alloc(16);
    float* c0      = (float*)alloc(256 * 4);
    float* c1      = (float*)alloc(256 * 4);
    float* crow0   = (float*)alloc(256 * 4);
    float* crow1   = (float*)alloc(256 * 4);

    auto S = [&](int i) { return pool + (long)i * SLOT; };
    __hip_bfloat16* xbf  = (__hip_bfloat16*)S(1);
    __hip_bfloat16* xT   = (__hip_bfloat16*)(S(1) + (long)BNR * DIN * 2);
    __hip_bfloat16* T0   = (__hip_bfloat16*)S(0);
    __hip_bfloat16* xg   = (__hip_bfloat16*)S(2);
    __hip_bfloat16* rg   = (__hip_bfloat16*)S(3);
    __hip_bfloat16* xwr  = (__hip_bfloat16*)S(0);   // xw_raw (pre-mix)
    __hip_bfloat16* rw0  = (__hip_bfloat16*)S(1);
    __hip_bfloat16* xwT  = (__hip_bfloat16*)S(2);   // xg dead
    __hip_bfloat16* T1   = (__hip_bfloat16*)S(3);   // rg dead
    __hip_bfloat16* xg1  = (__hip_bfloat16*)S(2);   // xwT dead after T1 gemm
    __hip_bfloat16* rg1  = (__hip_bfloat16*)S(4);
    __hip_bfloat16* orw  = (__hip_bfloat16*)S(0);   // xwr dead after dualmix
    __hip_bfloat16* rw1  = (__hip_bfloat16*)S(1);

    __hip_bfloat16* WresT = WT;             // 64x64
    __hip_bfloat16* Wg0T  = WT + 4096;      // 256x64
    __hip_bfloat16* Wrg0T = WT + 20480;     // 256x64
    __hip_bfloat16* Wc0T  = WT + 36864;     // 256x256 (coeff-scaled Wwo0^T)
    __hip_bfloat16* Wrw0T = WT + 102400;    // 256x64
    __hip_bfloat16* Wg1T  = WT + 118784;    // 256x256
    __hip_bfloat16* Wrg1T = WT + 184320;    // 256x64
    __hip_bfloat16* Wc1T  = WT + 200704;    // 64x256 (coeff-scaled Wwo1^T)
    __hip_bfloat16* Wrw1T = WT + 217088;    // 64x64

    const dim3 blk(256);
    const float invH = 1.0f / ((float)BNR * HH);
    const float invD = 1.0f / ((float)BNR * DOUT);

    // ---- prep: conversions, coeffs, folded weights, crow ----
    hipLaunchKernelGGL(coeff_k, dim3(1), dim3(256), 0, stream, logits0, gumb0, Wnl0, c0);
    hipLaunchKernelGGL(coeff_k, dim3(1), dim3(256), 0, stream, logits1, gumb1, Wnl1, c1);
    hipLaunchKernelGGL(cvt_k, dim3(2048), blk, 0, stream, x, (unsigned short*)xbf, (long)BNR * DIN / 4);
    hipLaunchKernelGGL(cvt_k, dim3(256), blk, 0, stream, adj, (unsigned short*)adjb, (long)NN * NN / 4);
    hipLaunchKernelGGL(tcvt_k, dim3(1, 8, 128), blk, 0, stream, x, (unsigned short*)xT, NN, DIN, (long)NN * DIN);

    WTArgs wa;
    wa.src[0] = Wres; wa.dst[0] = (unsigned short*)WresT; wa.cs[0] = nullptr; wa.R[0] = 64;  wa.C[0] = 64;
    wa.src[1] = Wg0;  wa.dst[1] = (unsigned short*)Wg0T;  wa.cs[1] = nullptr; wa.R[1] = 64;  wa.C[1] = 256;
    wa.src[2] = Wrg0; wa.dst[2] = (unsigned short*)Wrg0T; wa.cs[2] = nullptr; wa.R[2] = 64;  wa.C[2] = 256;
    wa.src[3] = Wwo0; wa.dst[3] = (unsigned short*)Wc0T;  wa.cs[3] = c0;      wa.R[3] = 256; wa.C[3] = 256;
    wa.src[4] = Wrw0; wa.dst[4] = (unsigned short*)Wrw0T; wa.cs[4] = nullptr; wa.R[4] = 64;  wa.C[4] = 256;
    wa.src[5] = Wg1;  wa.dst[5] = (unsigned short*)Wg1T;  wa.cs[5] = nullptr; wa.R[5] = 256; wa.C[5] = 256;
    wa.src[6] = Wrg1; wa.dst[6] = (unsigned short*)Wrg1T; wa.cs[6] = nullptr; wa.R[6] = 64;  wa.C[6] = 256;
    wa.src[7] = Wwo1; wa.dst[7] = (unsigned short*)Wc1T;  wa.cs[7] = c1;      wa.R[7] = 256; wa.C[7] = 64;
    wa.src[8] = Wrw1; wa.dst[8] = (unsigned short*)Wrw1T; wa.cs[8] = nullptr; wa.R[8] = 64;  wa.C[8] = 64;
    hipLaunchKernelGGL(tcvt_w_k, dim3(16, 9), blk, 0, stream, wa);

    hipLaunchKernelGGL(crow_k, dim3(HH), blk, 0, stream, Wwo0, bnl0, bwo0, crow0, HH, HH);
    hipLaunchKernelGGL(crow_k, dim3(DOUT), blk, 0, stream, Wwo1, bnl1, bwo1, crow1, HH, DOUT);

    // res = x @ Wres + bres
    hipLaunchKernelGGL((gemm_bt_k<128, 64, 4, 2>), dim3(1, BNR / 128, 1), blk, 0, stream,
                       xbf, WresT, bres, Rbf, BNR, DOUT, DIN, 0, 0, 0);

    // T0 = adj @ x (batched)
    hipLaunchKernelGGL((gemm_bt_k<128, 64, 4, 2>), dim3(1, 4, BB), blk, 0, stream,
                       adjb, xT, nullptr, T0, NN, DIN, NN, 0, (long)DIN * NN, (long)NN * DIN);

    // dual0: xg = T0@Wg0+bg0 ; rg = Rbf@Wrg0+brg0 (+diff)
    hipLaunchKernelGGL((dual_k<64, 128, 2, 4>), dim3(2, BNR / 64), blk, 0, stream,
                       T0, Wg0T, bg0, Rbf, Wrg0T, brg0, xg, rg, partial, BNR, HH, DIN, DOUT);
    hipLaunchKernelGGL(diff_final_k, dim3(1), blk, 0, stream, partial, 2048, th_s + 0, invH);

    // triple_w0: xwr = th0*(xg@Wc0)+om0*(rg@Wc0)+crow0+mix(xg,rg) ; rw0 = Rbf@Wrw0+brw0
    hipLaunchKernelGGL((triple_k<64, 128, 2, 4, true>), dim3(2, BNR / 64), blk, 0, stream,
                       xg, rg, Rbf, Wc0T, Wrw0T, th_s + 0, crow0, brw0,
                       xwr, rw0, partial, BNR, HH, HH, DOUT);
    hipLaunchKernelGGL(diff_final_k, dim3(1), blk, 0, stream, partial, 2048, th_s + 1, invH);

    // xwT = transpose(mix(xwr, rw0))
    hipLaunchKernelGGL(mixT_k, dim3(4, 8, BB), blk, 0, stream,
                       (const unsigned short*)xwr, (const unsigned short*)rw0, th_s + 1,
                       (unsigned short*)xwT);

    // T1 = adj @ xw (batched)
    hipLaunchKernelGGL((gemm_bt_k<128, 128, 4, 4>), dim3(2, 4, BB), blk, 0, stream,
                       adjb, xwT, nullptr, T1, NN, HH, NN, 0, (long)HH * NN, (long)NN * HH);

    // dual1: xg1 = T1@Wg1+bg1 + mix(xwr,rw0) ; rg1 = Rbf@Wrg1+brg1 (+diff)
    hipLaunchKernelGGL((dualmix_k<64, 128, 2, 4>), dim3(2, BNR / 64), blk, 0, stream,
                       T1, Wg1T, bg1, Rbf, Wrg1T, brg1,
                       xwr, rw0, th_s + 1, xg1, rg1, partial, BNR, HH, HH, DOUT);
    hipLaunchKernelGGL(diff_final_k, dim3(1), blk, 0, stream, partial, 2048, th_s + 2, invH);

    // triple_out: orw = th2*(xg1@Wc1)+om2*(rg1@Wc1)+crow1 ; rw1 = Rbf@Wrw1+brw1
    hipLaunchKernelGGL((triple_k<64, 64, 2, 2, false>), dim3(1, BNR / 64), blk, 0, stream,
                       xg1, rg1, Rbf, Wc1T, Wrw1T, th_s + 2, crow1, brw1,
                       orw, rw1, partial, BNR, DOUT, HH, DIN);
    hipLaunchKernelGGL(diff_final_k, dim3(1), blk, 0, stream, partial, 1024, th_s + 3, invD);

    // final mix -> fp32 out
    hipLaunchKernelGGL(mixfinal_k, dim3(2048), blk, 0, stream,
                       (const unsigned short*)orw, (const unsigned short*)rw1, th_s + 3,
                       out, (long)BNR * DOUT / 4);
}

// Round 7
// 207.282 us; speedup vs baseline: 1.7449x; 1.2360x over previous
//
#include <hip/hip_runtime.h>
#include <hip/hip_bf16.h>
#include <math.h>

#define BB   128
#define NN   512
#define DIN  64
#define HH   256
#define DOUT 64
#define BNR  (BB * NN)          // 65536 rows

typedef float  f32x4  __attribute__((ext_vector_type(4)));
typedef __bf16 bf16x8 __attribute__((ext_vector_type(8)));

#define GLP(p)  ((const __attribute__((address_space(1))) void*)(p))
#define LDSP(p) ((__attribute__((address_space(3))) void*)(p))

// Haar/db1 'zero' DWT patterns, levels 1..3, FULL_LEN=8
__constant__ float PAT[3][8] = {
    {0.70710678f, 0.70710678f, 0.f, 0.f, 0.f, 0.f, 0.f, 0.f},
    {0.5f,        0.70710678f, 0.f, 0.5f, 0.f, 0.f, 0.f, 0.f},
    {0.35355339f, 0.70710678f, 0.f, 0.f, 0.f, 0.5f, 0.f, 0.35355339f}
};

__device__ __forceinline__ unsigned short f2bfu(float x) {
    __hip_bfloat16 b = __float2bfloat16(x);
    unsigned short u;
    __builtin_memcpy(&u, &b, 2);
    return u;
}
__device__ __forceinline__ float bf2f(unsigned short u) {
    unsigned int v = ((unsigned int)u) << 16;
    float f;
    __builtin_memcpy(&f, &v, 4);
    return f;
}

// ---------------------------------------------------------------------------
// Coalesced bf16 tile write via LDS staging (verified round 4).
// ---------------------------------------------------------------------------
template<int BM, int BN, int FM, int FN>
__device__ __forceinline__ void write_tile(char* lds, f32x4 (&a)[FM][FN],
                                           __hip_bfloat16* __restrict__ C,
                                           long base, int N, int tid)
{
    const int wave = tid >> 6;
    const int lane = tid & 63;
    const int wm = wave >> 1, wn = wave & 1;
    const int lc = lane & 15;
    const int lr4 = (lane >> 4) << 2;
    __syncthreads();
    #pragma unroll
    for (int j = 0; j < FN; ++j) {
        int colb = (wn * (FN * 16) + j * 16 + lc) * 2;
        #pragma unroll
        for (int i = 0; i < FM; ++i) {
            int row0 = wm * (FM * 16) + i * 16 + lr4;
            #pragma unroll
            for (int r = 0; r < 4; ++r) {
                int row = row0 + r;
                *reinterpret_cast<unsigned short*>(
                    lds + row * (BN * 2) + (colb ^ (((row >> 2) & 3) << 5))) =
                    f2bfu(a[i][j][r]);
            }
        }
    }
    __syncthreads();
    const int TPR = BN / 8;
    const int RPP = 256 / TPR;
    #pragma unroll
    for (int p = 0; p < BM / RPP; ++p) {
        int row = p * RPP + tid / TPR;
        int cb = (tid % TPR) * 16;
        int pb = cb ^ (((row >> 2) & 3) << 5);
        uint4 v = *reinterpret_cast<const uint4*>(lds + row * (BN * 2) + pb);
        *reinterpret_cast<uint4*>(reinterpret_cast<char*>(C + base + (long)row * N) + cb) = v;
    }
}

// ---------------------------------------------------------------------------
// staging of one K=64 slab of A(BM rows) + B(BN rows) into swizzled LDS
// ---------------------------------------------------------------------------
template<int BM, int BN>
__device__ __forceinline__ void stage_tiles(const __hip_bfloat16* __restrict__ Ab,
                                            const __hip_bfloat16* __restrict__ Bb,
                                            char* AsB, char* BsB,
                                            int m0, int n0, int k0, int KA, int KB,
                                            int wave, int lane)
{
    const int NCH = (BM + BN) / 32;
    const int lr = lane >> 3;
    const int ls = lane & 7;
    #pragma unroll
    for (int cc = 0; cc < NCH; ++cc) {
        int c = wave * NCH + cc;
        const __hip_bfloat16* src;
        char* ldsb;
        if (c < BM / 8) {
            int r = c * 8 + lr;
            ldsb = AsB + c * 1024;
            src = Ab + ((long)(m0 + r) * KA + k0 + ((ls ^ (r & 7)) << 3));
        } else {
            int c2 = c - BM / 8;
            int r = c2 * 8 + lr;
            ldsb = BsB + c2 * 1024;
            src = Bb + ((long)(n0 + r) * KB + k0 + ((ls ^ (r & 7)) << 3));
        }
        __builtin_amdgcn_global_load_lds(GLP(src), LDSP(ldsb), 16, 0, 0);
    }
}

// compute 2 k-slices of MFMA from staged LDS into acc
template<int BM, int BN, int FM, int FN>
__device__ __forceinline__ void mfma_tiles(char* AsB, char* BsB,
                                           f32x4 (&acc)[FM][FN], int wave, int lane)
{
    const int wm = wave >> 1, wn = wave & 1;
    #pragma unroll
    for (int ksl = 0; ksl < 2; ++ksl) {
        bf16x8 af[FM], bfr[FN];
        #pragma unroll
        for (int i = 0; i < FM; ++i) {
            int row = wm * (FM * 16) + i * 16 + (lane & 15);
            int off = (ksl * 64 + ((lane >> 4) << 4)) ^ ((row & 7) << 4);
            af[i] = *reinterpret_cast<const bf16x8*>(AsB + row * 128 + off);
        }
        #pragma unroll
        for (int j = 0; j < FN; ++j) {
            int row = wn * (FN * 16) + j * 16 + (lane & 15);
            int off = (ksl * 64 + ((lane >> 4) << 4)) ^ ((row & 7) << 4);
            bfr[j] = *reinterpret_cast<const bf16x8*>(BsB + row * 128 + off);
        }
        #pragma unroll
        for (int i = 0; i < FM; ++i)
            #pragma unroll
            for (int j = 0; j < FN; ++j)
                acc[i][j] = __builtin_amdgcn_mfma_f32_16x16x32_bf16(
                    af[i], bfr[j], acc[i][j], 0, 0, 0);
    }
}

// ---------------------------------------------------------------------------
// fp32 -> bf16 convert
// ---------------------------------------------------------------------------
__global__ __launch_bounds__(256) void cvt_k(const float* __restrict__ in,
                                             unsigned short* __restrict__ out, long n4)
{
    long gid = (long)blockIdx.x * 256 + threadIdx.x;
    long stride = (long)gridDim.x * 256;
    for (long i = gid; i < n4; i += stride) {
        float4 v = reinterpret_cast<const float4*>(in)[i];
        ushort4 u;
        u.x = f2bfu(v.x); u.y = f2bfu(v.y); u.z = f2bfu(v.z); u.w = f2bfu(v.w);
        reinterpret_cast<ushort4*>(out)[i] = u;
    }
}

// ---------------------------------------------------------------------------
// transpose-convert fp32 (R,C) -> bf16 (C,R) with optional per-src-row scale
// ---------------------------------------------------------------------------
__device__ __forceinline__ void tcvt_body(const float* __restrict__ in,
                                          unsigned short* __restrict__ out,
                                          const float* __restrict__ cs,
                                          int R, int C, int r0, int c0)
{
    __shared__ float t[64][65];
    int tr = threadIdx.x >> 6;
    int tc = threadIdx.x & 63;
    #pragma unroll
    for (int i = 0; i < 16; ++i) {
        int r = i * 4 + tr;
        t[r][tc] = in[(long)(r0 + r) * C + c0 + tc];
    }
    __syncthreads();
    float sc = cs ? cs[r0 + tc] : 1.0f;
    #pragma unroll
    for (int i = 0; i < 16; ++i) {
        int r = i * 4 + tr;
        out[(long)(c0 + r) * R + r0 + tc] = f2bfu(t[tc][r] * sc);
    }
}

__global__ __launch_bounds__(256) void tcvt_k(const float* __restrict__ in,
                                              unsigned short* __restrict__ out,
                                              int R, int C, long sz)
{
    long base = (long)blockIdx.z * sz;
    tcvt_body(in + base, out + base, nullptr, R, C, blockIdx.y * 64, blockIdx.x * 64);
}

struct WTArgs {
    const float* src[8];
    unsigned short* dst[8];
    const float* cs[8];
    int R[8], C[8];
};
__global__ __launch_bounds__(256) void tcvt_w_k(WTArgs a)
{
    int wgt = blockIdx.y;
    int R = a.R[wgt], C = a.C[wgt];
    int tilesX = C >> 6;
    int tiles = (R >> 6) * tilesX;
    int t = blockIdx.x;
    if (t >= tiles) return;
    tcvt_body(a.src[wgt], a.dst[wgt], a.cs[wgt], R, C, (t / tilesX) * 64, (t % tilesX) * 64);
}

// ---------------------------------------------------------------------------
// wavelet coeff
// ---------------------------------------------------------------------------
__global__ void coeff_k(const float* __restrict__ logits, const float* __restrict__ gumb,
                        const float* __restrict__ Wnl, float* __restrict__ coeff)
{
    int f = threadIdx.x;
    float l0 = logits[0] + gumb[f * 3 + 0];
    float l1 = logits[1] + gumb[f * 3 + 1];
    float l2 = logits[2] + gumb[f * 3 + 2];
    int bl = 0;
    float bv = l0;
    if (l1 > bv) { bv = l1; bl = 1; }
    if (l2 > bv) { bv = l2; bl = 2; }
    float s = 0.f;
    #pragma unroll
    for (int t = 0; t < 8; ++t) s += Wnl[f * 8 + t] * PAT[bl][t];
    coeff[f] = s;
}

// ---------------------------------------------------------------------------
// batched vector folds: out[n] = (base? base[n]:0) + sum_k v[k]*(c?c[k]:1)*W[k,n]
// one block per (n, case); threads reduce over k. (round-5 lesson: parallel!)
// ---------------------------------------------------------------------------
struct FVArgs {
    const float* W[5];
    const float* c[5];
    const float* v[5];
    const float* base[5];
    float* out[5];
    int K[5], N[5];
};
__global__ __launch_bounds__(256) void foldvec_k(FVArgs a)
{
    int cs = blockIdx.y;
    int n = blockIdx.x;
    if (n >= a.N[cs]) return;
    int k = threadIdx.x;
    float s = 0.f;
    if (k < a.K[cs]) {
        float cc = a.c[cs] ? a.c[cs][k] : 1.0f;
        s = a.v[cs][k] * cc * a.W[cs][(long)k * a.N[cs] + n];
    }
    __shared__ float sm[256];
    sm[threadIdx.x] = s;
    __syncthreads();
    for (int o = 128; o > 0; o >>= 1) {
        if (threadIdx.x < o) sm[threadIdx.x] += sm[threadIdx.x + o];
        __syncthreads();
    }
    if (threadIdx.x == 0)
        a.out[cs][n] = (a.base[cs] ? a.base[cs][n] : 0.f) + sm[0];
}

// ---------------------------------------------------------------------------
// batched weight folds (transposed bf16 out, M=64 rows, K=256 fixed):
//   dstT[n,m] = (incl? Wsrc[m,n] : 0) + sum_k Wsrc[m,k]*c[k]*Wbig[k,n]
// one block per (m, case); thread n over N columns.
// ---------------------------------------------------------------------------
struct WFArgs {
    const float* Wsrc[3];
    const float* Wbig[3];
    const float* c[3];
    int incl[3], N[3];
    unsigned short* dst[3];
};
__global__ __launch_bounds__(256) void wfold_k(WFArgs a)
{
    int cs = blockIdx.y;
    int m = blockIdx.x;
    __shared__ float ws[256];
    ws[threadIdx.x] = a.Wsrc[cs][m * 256 + threadIdx.x] * a.c[cs][threadIdx.x];
    __syncthreads();
    int n = threadIdx.x;
    int N = a.N[cs];
    if (n >= N) return;
    float s = a.incl[cs] ? a.Wsrc[cs][m * 256 + n] : 0.f;
    const float* Wb = a.Wbig[cs];
    #pragma unroll 8
    for (int k = 0; k < 256; ++k)
        s += ws[k] * Wb[(long)k * N + n];
    a.dst[cs][n * 64 + m] = f2bfu(s);
}

// ---------------------------------------------------------------------------
// Single MFMA bf16 GEMM (bf16 out, coalesced epilogue)
// ---------------------------------------------------------------------------
template<int BM, int BN, int FM, int FN>
__global__ __launch_bounds__(256) void gemm_bt_k(
    const __hip_bfloat16* __restrict__ A, const __hip_bfloat16* __restrict__ Bt,
    const float* __restrict__ bias, __hip_bfloat16* __restrict__ Cb,
    int M, int N, int K, long sA, long sB, long sC)
{
    __shared__ __attribute__((aligned(128))) char lds[(BM + BN) * 128];
    char* AsB = lds;
    char* BsB = lds + BM * 128;

    const long bz = blockIdx.z;
    const __hip_bfloat16* Ab = A + bz * sA;
    const __hip_bfloat16* Bb = Bt + bz * sB;

    const int m0 = blockIdx.y * BM;
    const int n0 = blockIdx.x * BN;
    const int tid  = threadIdx.x;
    const int wave = tid >> 6;
    const int lane = tid & 63;
    const int wn = wave & 1;

    f32x4 acc[FM][FN];
    #pragma unroll
    for (int i = 0; i < FM; ++i)
        #pragma unroll
        for (int j = 0; j < FN; ++j)
            acc[i][j] = (f32x4){0.f, 0.f, 0.f, 0.f};

    for (int k0 = 0; k0 < K; k0 += 64) {
        stage_tiles<BM, BN>(Ab, Bb, AsB, BsB, m0, n0, k0, K, K, wave, lane);
        __syncthreads();
        mfma_tiles<BM, BN, FM, FN>(AsB, BsB, acc, wave, lane);
        __syncthreads();
    }

    const int lc = lane & 15;
    #pragma unroll
    for (int j = 0; j < FN; ++j) {
        int col = n0 + wn * (FN * 16) + j * 16 + lc;
        float bv = bias ? bias[col] : 0.0f;
        #pragma unroll
        for (int i = 0; i < FM; ++i)
            #pragma unroll
            for (int r = 0; r < 4; ++r)
                acc[i][j][r] += bv;
    }
    write_tile<BM, BN, FM, FN>(lds, acc, Cb, bz * sC + (long)m0 * N + n0, N, tid);
}

// ---------------------------------------------------------------------------
// Dual MFMA GEMM + in-register diff; C1/C2 nullable (partials-only mode)
// ---------------------------------------------------------------------------
template<int BM, int BN, int FM, int FN>
__global__ __launch_bounds__(256) void dual_k(
    const __hip_bfloat16* __restrict__ A1, const __hip_bfloat16* __restrict__ B1t,
    const float* __restrict__ bias1,
    const __hip_bfloat16* __restrict__ A2, const __hip_bfloat16* __restrict__ B2t,
    const float* __restrict__ bias2,
    __hip_bfloat16* __restrict__ C1, __hip_bfloat16* __restrict__ C2,
    float* __restrict__ partial,
    int M, int N, int K1, int K2)
{
    __shared__ __attribute__((aligned(128))) char lds[(BM + BN) * 128];
    char* AsB = lds;
    char* BsB = lds + BM * 128;

    const int m0 = blockIdx.y * BM;
    const int n0 = blockIdx.x * BN;
    const int tid  = threadIdx.x;
    const int wave = tid >> 6;
    const int lane = tid & 63;
    const int wn = wave & 1;

    f32x4 acc[2][FM][FN];
    #pragma unroll
    for (int p = 0; p < 2; ++p)
        #pragma unroll
        for (int i = 0; i < FM; ++i)
            #pragma unroll
            for (int j = 0; j < FN; ++j)
                acc[p][i][j] = (f32x4){0.f, 0.f, 0.f, 0.f};

    #pragma unroll
    for (int ph = 0; ph < 2; ++ph) {
        const __hip_bfloat16* Ab = ph ? A2 : A1;
        const __hip_bfloat16* Bb = ph ? B2t : B1t;
        const int K = ph ? K2 : K1;
        for (int k0 = 0; k0 < K; k0 += 64) {
            stage_tiles<BM, BN>(Ab, Bb, AsB, BsB, m0, n0, k0, K, K, wave, lane);
            __syncthreads();
            mfma_tiles<BM, BN, FM, FN>(AsB, BsB, acc[ph], wave, lane);
            __syncthreads();
        }
    }

    const int lc  = lane & 15;
    float dsum = 0.f;
    #pragma unroll
    for (int j = 0; j < FN; ++j) {
        int col = n0 + wn * (FN * 16) + j * 16 + lc;
        float b1 = bias1 ? bias1[col] : 0.0f;
        float b2 = bias2 ? bias2[col] : 0.0f;
        #pragma unroll
        for (int i = 0; i < FM; ++i)
            #pragma unroll
            for (int r = 0; r < 4; ++r) {
                float v1 = acc[0][i][j][r] + b1;
                float v2 = acc[1][i][j][r] + b2;
                acc[0][i][j][r] = v1;
                acc[1][i][j][r] = v2;
                float d = v1 - v2;
                dsum += d * d;
            }
    }

    float* red = (float*)lds;
    red[tid] = dsum;
    __syncthreads();
    for (int o = 128; o > 0; o >>= 1) {
        if (tid < o) red[tid] += red[tid + o];
        __syncthreads();
    }
    if (tid == 0) partial[blockIdx.y * gridDim.x + blockIdx.x] = red[0];

    if (C1) write_tile<BM, BN, FM, FN>(lds, acc[0], C1, (long)m0 * N + n0, N, tid);
    if (C2) write_tile<BM, BN, FM, FN>(lds, acc[1], C2, (long)m0 * N + n0, N, tid);
}

// ---------------------------------------------------------------------------
// wave_k: 3-phase MFMA with th-combine epilogue (layer-0 wavelet + final):
//   C1 = th*(P0 + b0) + om*(P1 + b1) + crow[col]
//   C2 = P2 + b2[col]
//   partial += (C1-C2)^2
// ---------------------------------------------------------------------------
template<int BM, int BN, int FM, int FN>
__global__ __launch_bounds__(256) void wave_k(
    const __hip_bfloat16* __restrict__ A0, const __hip_bfloat16* __restrict__ B0,
    int K0, const float* __restrict__ b0,
    const __hip_bfloat16* __restrict__ A1, const __hip_bfloat16* __restrict__ B1,
    int K1, const float* __restrict__ b1,
    const __hip_bfloat16* __restrict__ A2, const __hip_bfloat16* __restrict__ B2,
    int K2, const float* __restrict__ b2,
    const float* __restrict__ th_p, const float* __restrict__ crow,
    __hip_bfloat16* __restrict__ C1, __hip_bfloat16* __restrict__ C2,
    float* __restrict__ partial, int M, int N)
{
    __shared__ __attribute__((aligned(128))) char lds[(BM + BN) * 128];
    char* AsB = lds;
    char* BsB = lds + BM * 128;

    const float th = th_p[0];
    const float om = 1.f - th;

    const int m0 = blockIdx.y * BM;
    const int n0 = blockIdx.x * BN;
    const int tid  = threadIdx.x;
    const int wave = tid >> 6;
    const int lane = tid & 63;
    const int wn = wave & 1;

    f32x4 acc[3][FM][FN];
    #pragma unroll
    for (int p = 0; p < 3; ++p)
        #pragma unroll
        for (int i = 0; i < FM; ++i)
            #pragma unroll
            for (int j = 0; j < FN; ++j)
                acc[p][i][j] = (f32x4){0.f, 0.f, 0.f, 0.f};

    #pragma unroll
    for (int ph = 0; ph < 3; ++ph) {
        const __hip_bfloat16* Ab = (ph == 0) ? A0 : (ph == 1 ? A1 : A2);
        const __hip_bfloat16* Bb = (ph == 0) ? B0 : (ph == 1 ? B1 : B2);
        const int K = (ph == 0) ? K0 : (ph == 1 ? K1 : K2);
        for (int k0 = 0; k0 < K; k0 += 64) {
            stage_tiles<BM, BN>(Ab, Bb, AsB, BsB, m0, n0, k0, K, K, wave, lane);
            __syncthreads();
            mfma_tiles<BM, BN, FM, FN>(AsB, BsB, acc[ph], wave, lane);
            __syncthreads();
        }
    }

    const int lc = lane & 15;
    float dsum = 0.f;
    #pragma unroll
    for (int j = 0; j < FN; ++j) {
        int col = n0 + wn * (FN * 16) + j * 16 + lc;
        float bv0 = b0 ? b0[col] : 0.0f;
        float bv1 = b1 ? b1[col] : 0.0f;
        float bv2 = b2 ? b2[col] : 0.0f;
        float cr  = crow[col];
        #pragma unroll
        for (int i = 0; i < FM; ++i)
            #pragma unroll
            for (int r = 0; r < 4; ++r) {
                float v1 = th * (acc[0][i][j][r] + bv0) + om * (acc[1][i][j][r] + bv1) + cr;
                float v2 = acc[2][i][j][r] + bv2;
                acc[0][i][j][r] = v1;
                acc[2][i][j][r] = v2;
                float d = v1 - v2;
                dsum += d * d;
            }
    }

    float* red = (float*)lds;
    red[tid] = dsum;
    __syncthreads();
    for (int o = 128; o > 0; o >>= 1) {
        if (tid < o) red[tid] += red[tid + o];
        __syncthreads();
    }
    if (tid == 0) partial[blockIdx.y * gridDim.x + blockIdx.x] = red[0];

    write_tile<BM, BN, FM, FN>(lds, acc[0], C1, (long)m0 * N + n0, N, tid);
    write_tile<BM, BN, FM, FN>(lds, acc[2], C2, (long)m0 * N + n0, N, tid);
}

// ---------------------------------------------------------------------------
// gmix_k: xg1 = P0 + b0 + th*mixG[m,n] + om*(P2 + b2); rg1 = P1 + b1 (unwritten)
// partial += (xg1-rg1)^2; write only C1. mixG read coalesced via f32 LDS stage.
// ---------------------------------------------------------------------------
template<int BM, int BN, int FM, int FN>
__global__ __launch_bounds__(256) void gmix_k(
    const __hip_bfloat16* __restrict__ A0, const __hip_bfloat16* __restrict__ B0,
    int K0, const float* __restrict__ b0,
    const __hip_bfloat16* __restrict__ A1, const __hip_bfloat16* __restrict__ B1,
    int K1, const float* __restrict__ b1,
    const __hip_bfloat16* __restrict__ A2, const __hip_bfloat16* __restrict__ B2,
    int K2, const float* __restrict__ b2,
    const __hip_bfloat16* __restrict__ mixG, const float* __restrict__ th_p,
    __hip_bfloat16* __restrict__ C1, float* __restrict__ partial, int M, int N)
{
    __shared__ __attribute__((aligned(128))) char lds[BM * BN * 4];
    char* AsB = lds;
    char* BsB = lds + BM * 128;

    const float th = th_p[0];
    const float om = 1.f - th;

    const int m0 = blockIdx.y * BM;
    const int n0 = blockIdx.x * BN;
    const int tid  = threadIdx.x;
    const int wave = tid >> 6;
    const int lane = tid & 63;
    const int wm = wave >> 1, wn = wave & 1;

    f32x4 acc[3][FM][FN];
    #pragma unroll
    for (int p = 0; p < 3; ++p)
        #pragma unroll
        for (int i = 0; i < FM; ++i)
            #pragma unroll
            for (int j = 0; j < FN; ++j)
                acc[p][i][j] = (f32x4){0.f, 0.f, 0.f, 0.f};

    #pragma unroll
    for (int ph = 0; ph < 3; ++ph) {
        const __hip_bfloat16* Ab = (ph == 0) ? A0 : (ph == 1 ? A1 : A2);
        const __hip_bfloat16* Bb = (ph == 0) ? B0 : (ph == 1 ? B1 : B2);
        const int K = (ph == 0) ? K0 : (ph == 1 ? K1 : K2);
        for (int k0 = 0; k0 < K; k0 += 64) {
            stage_tiles<BM, BN>(Ab, Bb, AsB, BsB, m0, n0, k0, K, K, wave, lane);
            __syncthreads();
            mfma_tiles<BM, BN, FM, FN>(AsB, BsB, acc[ph], wave, lane);
            __syncthreads();
        }
    }

    const int lc  = lane & 15;
    const int lr4 = (lane >> 4) << 2;
    float* ldsf = (float*)lds;
    const int TPR = BN / 8;
    const int RPP = 256 / TPR;
    const int NP  = BM / RPP;

    // pass 1: base1 = P0 + b0 + om*(P2 + b2) -> LDS; add th*mixG coalesced
    #pragma unroll
    for (int j = 0; j < FN; ++j) {
        int col = n0 + wn * (FN * 16) + j * 16 + lc;
        float bv0 = b0 ? b0[col] : 0.0f;
        float bv2 = b2 ? b2[col] : 0.0f;
        #pragma unroll
        for (int i = 0; i < FM; ++i) {
            int rowb = wm * (FM * 16) + i * 16 + lr4;
            #pragma unroll
            for (int r = 0; r < 4; ++r)
                ldsf[(rowb + r) * BN + wn * (FN * 16) + j * 16 + lc] =
                    acc[0][i][j][r] + bv0 + om * (acc[2][i][j][r] + bv2);
        }
    }
    __syncthreads();

    float v1k[NP][8];
    float dsum = 0.f;
    #pragma unroll
    for (int p = 0; p < NP; ++p) {
        int row = p * RPP + tid / TPR;
        int cole = (tid % TPR) * 8;
        long gidx = (long)(m0 + row) * N + n0 + cole;
        uint4 ma = *reinterpret_cast<const uint4*>(mixG + gidx);
        unsigned int outp[4];
        #pragma unroll
        for (int q = 0; q < 4; ++q) {
            unsigned int wa = (&ma.x)[q];
            float v0 = ldsf[row * BN + cole + q * 2] + th * bf2f((unsigned short)wa);
            float v1 = ldsf[row * BN + cole + q * 2 + 1] + th * bf2f((unsigned short)(wa >> 16));
            v1k[p][q * 2] = v0;
            v1k[p][q * 2 + 1] = v1;
            outp[q] = (unsigned int)f2bfu(v0) | ((unsigned int)f2bfu(v1) << 16);
        }
        *reinterpret_cast<uint4*>(C1 + gidx) = make_uint4(outp[0], outp[1], outp[2], outp[3]);
    }
    __syncthreads();

    // pass 2: v2 = P1 + b1 -> LDS; diff vs kept v1
    #pragma unroll
    for (int j = 0; j < FN; ++j) {
        int col = n0 + wn * (FN * 16) + j * 16 + lc;
        float bv1 = b1 ? b1[col] : 0.0f;
        #pragma unroll
        for (int i = 0; i < FM; ++i) {
            int rowb = wm * (FM * 16) + i * 16 + lr4;
            #pragma unroll
            for (int r = 0; r < 4; ++r)
                ldsf[(rowb + r) * BN + wn * (FN * 16) + j * 16 + lc] = acc[1][i][j][r] + bv1;
        }
    }
    __syncthreads();

    #pragma unroll
    for (int p = 0; p < NP; ++p) {
        int row = p * RPP + tid / TPR;
        int cole = (tid % TPR) * 8;
        #pragma unroll
        for (int q = 0; q < 8; ++q) {
            float d = v1k[p][q] - ldsf[row * BN + cole + q];
            dsum += d * d;
        }
    }
    __syncthreads();

    float* red = (float*)lds;
    red[tid] = dsum;
    __syncthreads();
    for (int o = 128; o > 0; o >>= 1) {
        if (tid < o) red[tid] += red[tid + o];
        __syncthreads();
    }
    if (tid == 0) partial[blockIdx.y * gridDim.x + blockIdx.x] = red[0];
}

// ---------------------------------------------------------------------------
// th = sigmoid(sum(partial)/n)
// ---------------------------------------------------------------------------
__global__ __launch_bounds__(256) void diff_final_k(
    const float* __restrict__ partial, int np, float* __restrict__ th_out, float inv_n)
{
    float s = 0.f;
    for (int i = threadIdx.x; i < np; i += 256) s += partial[i];
    __shared__ float sm[256];
    sm[threadIdx.x] = s;
    __syncthreads();
    for (int o = 128; o > 0; o >>= 1) {
        if (threadIdx.x < o) sm[threadIdx.x] += sm[threadIdx.x + o];
        __syncthreads();
    }
    if (threadIdx.x == 0) {
        float d = sm[0] * inv_n;
        th_out[0] = 1.f / (1.f + expf(-d));
    }
}

// ---------------------------------------------------------------------------
// mix + batched transpose, writes xwT (b,H,N) — vectorized ushort4 I/O
// ---------------------------------------------------------------------------
__global__ __launch_bounds__(256) void mixT_k(
    const unsigned short* __restrict__ h, const unsigned short* __restrict__ r,
    const float* __restrict__ th_p, unsigned short* __restrict__ xwT)
{
    const float th = th_p[0];
    const float om = 1.f - th;
    __shared__ float t[64][65];
    const long base = (long)blockIdx.z * NN * HH;
    const int r0 = blockIdx.y * 64;
    const int c0 = blockIdx.x * 64;
    const int tr  = threadIdx.x >> 4;
    const int tc4 = (threadIdx.x & 15) * 4;
    #pragma unroll
    for (int i = 0; i < 4; ++i) {
        int rr = i * 16 + tr;
        long idx = base + (long)(r0 + rr) * HH + c0 + tc4;
        ushort4 hv = *reinterpret_cast<const ushort4*>(h + idx);
        ushort4 rv = *reinterpret_cast<const ushort4*>(r + idx);
        t[rr][tc4 + 0] = th * bf2f(hv.x) + om * bf2f(rv.x);
        t[rr][tc4 + 1] = th * bf2f(hv.y) + om * bf2f(rv.y);
        t[rr][tc4 + 2] = th * bf2f(hv.z) + om * bf2f(rv.z);
        t[rr][tc4 + 3] = th * bf2f(hv.w) + om * bf2f(rv.w);
    }
    __syncthreads();
    #pragma unroll
    for (int i = 0; i < 4; ++i) {
        int cc = i * 16 + tr;
        ushort4 v;
        v.x = f2bfu(t[tc4 + 0][cc]);
        v.y = f2bfu(t[tc4 + 1][cc]);
        v.z = f2bfu(t[tc4 + 2][cc]);
        v.w = f2bfu(t[tc4 + 3][cc]);
        *reinterpret_cast<ushort4*>(xwT + base + (long)(c0 + cc) * NN + r0 + tc4) = v;
    }
}

// ---------------------------------------------------------------------------
// final mix: out = th*h + (1-th)*r, fp32 out
// ---------------------------------------------------------------------------
__global__ __launch_bounds__(256) void mixfinal_k(
    const unsigned short* __restrict__ h, const unsigned short* __restrict__ r,
    const float* __restrict__ th_p, float* __restrict__ out, long n4)
{
    const float th = th_p[0];
    const float om = 1.f - th;
    long gid = (long)blockIdx.x * 256 + threadIdx.x;
    long stride = (long)gridDim.x * 256;
    for (long i = gid; i < n4; i += stride) {
        ushort4 hv = reinterpret_cast<const ushort4*>(h)[i];
        ushort4 rv = reinterpret_cast<const ushort4*>(r)[i];
        float4 o;
        o.x = th * bf2f(hv.x) + om * bf2f(rv.x);
        o.y = th * bf2f(hv.y) + om * bf2f(rv.y);
        o.z = th * bf2f(hv.z) + om * bf2f(rv.z);
        o.w = th * bf2f(hv.w) + om * bf2f(rv.w);
        reinterpret_cast<float4*>(out)[i] = o;
    }
}

// ---------------------------------------------------------------------------
extern "C" void kernel_launch(void* const* d_in, const int* in_sizes, int n_in,
                              void* d_out, int out_size, void* d_ws, size_t ws_size,
                              hipStream_t stream)
{
    const float* x       = (const float*)d_in[0];
    const float* adj     = (const float*)d_in[1];
    const float* Wres    = (const float*)d_in[2];
    const float* bres    = (const float*)d_in[3];
    const float* Wg0     = (const float*)d_in[4];
    const float* bg0     = (const float*)d_in[5];
    const float* Wrg0    = (const float*)d_in[6];
    const float* brg0    = (const float*)d_in[7];
    const float* logits0 = (const float*)d_in[8];
    const float* gumb0   = (const float*)d_in[9];
    const float* Wnl0    = (const float*)d_in[10];
    const float* bnl0    = (const float*)d_in[11];
    const float* Wwo0    = (const float*)d_in[12];
    const float* bwo0    = (const float*)d_in[13];
    const float* Wrw0    = (const float*)d_in[14];
    const float* brw0    = (const float*)d_in[15];
    const float* Wg1     = (const float*)d_in[16];
    const float* bg1     = (const float*)d_in[17];
    const float* Wrg1    = (const float*)d_in[18];
    const float* brg1    = (const float*)d_in[19];
    const float* logits1 = (const float*)d_in[20];
    const float* gumb1   = (const float*)d_in[21];
    const float* Wnl1    = (const float*)d_in[22];
    const float* bnl1    = (const float*)d_in[23];
    const float* Wwo1    = (const float*)d_in[24];
    const float* bwo1    = (const float*)d_in[25];
    const float* Wrw1    = (const float*)d_in[26];
    const float* brw1    = (const float*)d_in[27];

    float* out = (float*)d_out;

    // ---- workspace ----
    char* w = (char*)d_ws;
    auto alloc = [&](long bytes) { char* p = w; w += (bytes + 255) & ~255L; return p; };
    const long SLOT = (long)BNR * HH * 2;                 // 32 MB
    char* pool = alloc(5 * SLOT);                         // 160 MB
    __hip_bfloat16* Rbf  = (__hip_bfloat16*)alloc((long)BNR * DOUT * 2); // 8 MB
    __hip_bfloat16* adjb = (__hip_bfloat16*)alloc((long)NN * NN * 2);
    __hip_bfloat16* WT   = (__hip_bfloat16*)alloc(192512L * 2);
    float* partial = (float*)alloc(4096 * 4);
    float* th_s    = (float*)alloc(16);
    float* c0      = (float*)alloc(256 * 4);
    float* c1      = (float*)alloc(256 * 4);
    float* bg0p    = (float*)alloc(256 * 4);
    float* brg0p   = (float*)alloc(256 * 4);
    float* crow0   = (float*)alloc(256 * 4);
    float* brgc1   = (float*)alloc(64 * 4);
    float* crow1   = (float*)alloc(64 * 4);

    auto S = [&](int i) { return pool + (long)i * SLOT; };
    __hip_bfloat16* xwr = (__hip_bfloat16*)S(0);
    __hip_bfloat16* rw0 = (__hip_bfloat16*)S(1);
    __hip_bfloat16* orw = (__hip_bfloat16*)S(1);                      // after rw0 dead
    __hip_bfloat16* rw1 = (__hip_bfloat16*)(S(1) + (long)BNR * DOUT * 2);
    __hip_bfloat16* xwT = (__hip_bfloat16*)S(2);
    __hip_bfloat16* xg1 = (__hip_bfloat16*)S(2);                      // after xwT dead
    __hip_bfloat16* T1  = (__hip_bfloat16*)S(3);
    __hip_bfloat16* xbf = (__hip_bfloat16*)S(4);
    __hip_bfloat16* xT  = (__hip_bfloat16*)(S(4) + (long)BNR * DIN * 2);
    __hip_bfloat16* T0  = (__hip_bfloat16*)(S(4) + 2L * BNR * DIN * 2);

    // transposed weights inside WT (element offsets)
    __hip_bfloat16* WresT  = WT;             // 64x64
    __hip_bfloat16* Wg0T   = WT + 4096;      // 256x64
    __hip_bfloat16* Wrg0T  = WT + 20480;     // 256x64
    __hip_bfloat16* Wrw0T  = WT + 36864;     // 256x64
    __hip_bfloat16* Wg1T   = WT + 53248;     // 256x256
    __hip_bfloat16* Wrg1T  = WT + 118784;    // 256x64
    __hip_bfloat16* Wc1T   = WT + 135168;    // 64x256 (c1-scaled Wwo1^T)
    __hip_bfloat16* Wrw1T  = WT + 151552;    // 64x64
    __hip_bfloat16* Wg0pT  = WT + 155648;    // 256x64 (Wg0@(I+Wc0))^T
    __hip_bfloat16* Wrg0pT = WT + 172032;    // 256x64 (Wrg0@(I+Wc0))^T
    __hip_bfloat16* Wrgc1T = WT + 188416;    // 64x64  (Wrg1@Wc1)^T

    const dim3 blk(256);
    const float invH = 1.0f / ((float)BNR * HH);
    const float invD = 1.0f / ((float)BNR * DOUT);

    // ---- prep ----
    hipLaunchKernelGGL(coeff_k, dim3(1), dim3(256), 0, stream, logits0, gumb0, Wnl0, c0);
    hipLaunchKernelGGL(coeff_k, dim3(1), dim3(256), 0, stream, logits1, gumb1, Wnl1, c1);
    hipLaunchKernelGGL(cvt_k, dim3(2048), blk, 0, stream, x, (unsigned short*)xbf, (long)BNR * DIN / 4);
    hipLaunchKernelGGL(cvt_k, dim3(256), blk, 0, stream, adj, (unsigned short*)adjb, (long)NN * NN / 4);
    hipLaunchKernelGGL(tcvt_k, dim3(1, 8, 128), blk, 0, stream, x, (unsigned short*)xT, NN, DIN, (long)NN * DIN);

    WTArgs wa;
    wa.src[0] = Wres; wa.dst[0] = (unsigned short*)WresT; wa.cs[0] = nullptr; wa.R[0] = 64;  wa.C[0] = 64;
    wa.src[1] = Wg0;  wa.dst[1] = (unsigned short*)Wg0T;  wa.cs[1] = nullptr; wa.R[1] = 64;  wa.C[1] = 256;
    wa.src[2] = Wrg0; wa.dst[2] = (unsigned short*)Wrg0T; wa.cs[2] = nullptr; wa.R[2] = 64;  wa.C[2] = 256;
    wa.src[3] = Wrw0; wa.dst[3] = (unsigned short*)Wrw0T; wa.cs[3] = nullptr; wa.R[3] = 64;  wa.C[3] = 256;
    wa.src[4] = Wg1;  wa.dst[4] = (unsigned short*)Wg1T;  wa.cs[4] = nullptr; wa.R[4] = 256; wa.C[4] = 256;
    wa.src[5] = Wrg1; wa.dst[5] = (unsigned short*)Wrg1T; wa.cs[5] = nullptr; wa.R[5] = 64;  wa.C[5] = 256;
    wa.src[6] = Wwo1; wa.dst[6] = (unsigned short*)Wc1T;  wa.cs[6] = c1;      wa.R[6] = 256; wa.C[6] = 64;
    wa.src[7] = Wrw1; wa.dst[7] = (unsigned short*)Wrw1T; wa.cs[7] = nullptr; wa.R[7] = 64;  wa.C[7] = 64;
    hipLaunchKernelGGL(tcvt_w_k, dim3(16, 8), blk, 0, stream, wa);

    WFArgs wf;
    wf.Wsrc[0] = Wg0;  wf.Wbig[0] = Wwo0; wf.c[0] = c0; wf.incl[0] = 1; wf.N[0] = 256;
    wf.dst[0] = (unsigned short*)Wg0pT;
    wf.Wsrc[1] = Wrg0; wf.Wbig[1] = Wwo0; wf.c[1] = c0; wf.incl[1] = 1; wf.N[1] = 256;
    wf.dst[1] = (unsigned short*)Wrg0pT;
    wf.Wsrc[2] = Wrg1; wf.Wbig[2] = Wwo1; wf.c[2] = c1; wf.incl[2] = 0; wf.N[2] = 64;
    wf.dst[2] = (unsigned short*)Wrgc1T;
    hipLaunchKernelGGL(wfold_k, dim3(64, 3), blk, 0, stream, wf);

    FVArgs fv;
    fv.W[0] = Wwo0; fv.c[0] = c0;      fv.v[0] = bg0;  fv.base[0] = bg0;  fv.out[0] = bg0p;  fv.K[0] = 256; fv.N[0] = 256;
    fv.W[1] = Wwo0; fv.c[1] = c0;      fv.v[1] = brg0; fv.base[1] = brg0; fv.out[1] = brg0p; fv.K[1] = 256; fv.N[1] = 256;
    fv.W[2] = Wwo0; fv.c[2] = nullptr; fv.v[2] = bnl0; fv.base[2] = bwo0; fv.out[2] = crow0; fv.K[2] = 256; fv.N[2] = 256;
    fv.W[3] = Wwo1; fv.c[3] = c1;      fv.v[3] = brg1; fv.base[3] = nullptr; fv.out[3] = brgc1; fv.K[3] = 256; fv.N[3] = 64;
    fv.W[4] = Wwo1; fv.c[4] = nullptr; fv.v[4] = bnl1; fv.base[4] = bwo1; fv.out[4] = crow1; fv.K[4] = 256; fv.N[4] = 64;
    hipLaunchKernelGGL(foldvec_k, dim3(256, 5), blk, 0, stream, fv);

    // res = x @ Wres + bres
    hipLaunchKernelGGL((gemm_bt_k<128, 64, 4, 2>), dim3(1, BNR / 128, 1), blk, 0, stream,
                       xbf, WresT, bres, Rbf, BNR, DOUT, DIN, 0, 0, 0);

    // T0 = adj @ x (batched)
    hipLaunchKernelGGL((gemm_bt_k<128, 64, 4, 2>), dim3(1, 4, BB), blk, 0, stream,
                       adjb, xT, nullptr, T0, NN, DIN, NN, 0, (long)DIN * NN, (long)NN * DIN);

    // D0: diff0 partials only (xg vs rg, never materialized)
    hipLaunchKernelGGL((dual_k<64, 128, 2, 4>), dim3(2, BNR / 64), blk, 0, stream,
                       T0, Wg0T, bg0, Rbf, Wrg0T, brg0,
                       (__hip_bfloat16*)nullptr, (__hip_bfloat16*)nullptr,
                       partial, BNR, HH, DIN, DOUT);
    hipLaunchKernelGGL(diff_final_k, dim3(1), blk, 0, stream, partial, 2048, th_s + 0, invH);

    // W0: xwr = th0*(T0@Wg0p+bg0p)+om0*(Rbf@Wrg0p+brg0p)+crow0 ; rw0 = Rbf@Wrw0+brw0
    hipLaunchKernelGGL((wave_k<64, 128, 2, 4>), dim3(2, BNR / 64), blk, 0, stream,
                       T0, Wg0pT, DIN, bg0p,
                       Rbf, Wrg0pT, DOUT, brg0p,
                       Rbf, Wrw0T, DOUT, brw0,
                       th_s + 0, crow0, xwr, rw0, partial, BNR, HH);
    hipLaunchKernelGGL(diff_final_k, dim3(1), blk, 0, stream, partial, 2048, th_s + 1, invH);

    // xwT = transpose(mix(xwr, rw0))
    hipLaunchKernelGGL(mixT_k, dim3(4, 8, BB), blk, 0, stream,
                       (const unsigned short*)xwr, (const unsigned short*)rw0, th_s + 1,
                       (unsigned short*)xwT);

    // T1 = adj @ xw (batched)
    hipLaunchKernelGGL((gemm_bt_k<128, 128, 4, 4>), dim3(2, 4, BB), blk, 0, stream,
                       adjb, xwT, nullptr, T1, NN, HH, NN, 0, (long)HH * NN, (long)NN * HH);

    // DM1: xg1 = T1@Wg1+bg1 + th1*xwr + om1*(Rbf@Wrw0+brw0); rg1 in-reg (diff only)
    hipLaunchKernelGGL((gmix_k<64, 128, 2, 4>), dim3(2, BNR / 64), blk, 0, stream,
                       T1, Wg1T, HH, bg1,
                       Rbf, Wrg1T, DOUT, brg1,
                       Rbf, Wrw0T, DOUT, brw0,
                       xwr, th_s + 1, xg1, partial, BNR, HH);
    hipLaunchKernelGGL(diff_final_k, dim3(1), blk, 0, stream, partial, 2048, th_s + 2, invH);

    // F: orw = th2*(xg1@Wc1) + om2*(Rbf@Wrgc1+brgc1) + crow1 ; rw1 = Rbf@Wrw1+brw1
    hipLaunchKernelGGL((wave_k<64, 64, 2, 2>), dim3(1, BNR / 64), blk, 0, stream,
                       xg1, Wc1T, HH, (const float*)nullptr,
                       Rbf, Wrgc1T, DOUT, brgc1,
                       Rbf, Wrw1T, DIN, brw1,
                       th_s + 2, crow1, orw, rw1, partial, BNR, DOUT);
    hipLaunchKernelGGL(diff_final_k, dim3(1), blk, 0, stream, partial, 1024, th_s + 3, invD);

    // final mix -> fp32 out
    hipLaunchKernelGGL(mixfinal_k, dim3(2048), blk, 0, stream,
                       (const unsigned short*)orw, (const unsigned short*)rw1, th_s + 3,
                       out, (long)BNR * DOUT / 4);
}